// Round 6
// baseline (601.041 us; speedup 1.0000x reference)
//
#include <hip/hip_runtime.h>
#include <math.h>

#define S_ 4096
#define V_ 10000
#define E_ 128
#define H_ 256
#define NE_ 4
#define NH_ 4
#define HD_ 64
#define FF_ 2048
#define NL_ 2
#define EPS_ 1e-5f
#define SCALE_ 0.125f
#define SPLITS_ 4
#define PSTRIDE_ 160   // 79 col-blocks * 2 wave-halves = 158, padded

typedef __attribute__((ext_vector_type(8))) short bf16x8;
typedef __attribute__((ext_vector_type(4))) float f32x4;

static __device__ __forceinline__ short f2bf(float f) {
  unsigned u = __builtin_bit_cast(unsigned, f);
  unsigned r = (u + 0x7fffu + ((u >> 16) & 1u)) >> 16;
  return (short)r;
}
static __device__ __forceinline__ float bf2f(short s) {
  unsigned u = ((unsigned)(unsigned short)s) << 16;
  return __builtin_bit_cast(float, u);
}

// ---------------- weight fp32 -> bf16 pre-convert + embedding gather ----------------
struct CvtArgs {
  const float* src[9];
  short* dst[9];
  int pfx[10];
};
__global__ __launch_bounds__(256) void k_cvt(CvtArgs a, const int* __restrict__ x,
                                             const float* __restrict__ emb,
                                             short* __restrict__ h) {
  int b = blockIdx.x;
  if (b >= a.pfx[9]) {
    int i8 = (b - a.pfx[9]) * 2048 + threadIdx.x * 8;
    int s = i8 >> 7, e = i8 & 127;
    const float* sp = &emb[(size_t)x[s] * E_ + e];
    float4 v0 = *(const float4*)sp;
    float4 v1 = *(const float4*)(sp + 4);
    short4 o0, o1;
    o0.x = f2bf(v0.x); o0.y = f2bf(v0.y); o0.z = f2bf(v0.z); o0.w = f2bf(v0.w);
    o1.x = f2bf(v1.x); o1.y = f2bf(v1.y); o1.z = f2bf(v1.z); o1.w = f2bf(v1.w);
    *(short4*)&h[i8] = o0;
    *(short4*)&h[i8 + 4] = o1;
    return;
  }
  int s = 0;
  while (b >= a.pfx[s + 1]) ++s;
  size_t base = (size_t)(b - a.pfx[s]) * 2048 + threadIdx.x * 8;
  const float* sp = a.src[s] + base;
  short* dp = a.dst[s] + base;
  float4 v0 = *(const float4*)sp;
  float4 v1 = *(const float4*)(sp + 4);
  short4 o0, o1;
  o0.x = f2bf(v0.x); o0.y = f2bf(v0.y); o0.z = f2bf(v0.z); o0.w = f2bf(v0.w);
  o1.x = f2bf(v1.x); o1.y = f2bf(v1.y); o1.z = f2bf(v1.z); o1.w = f2bf(v1.w);
  *(short4*)dp = o0;
  *(short4*)(dp + 4) = o1;
}

// ---------------- 64x64-tile bf16 GEMM, BK=64 (qkv) ----------------
template <int ACT>
__global__ __launch_bounds__(256) void k_gemm64(const short* __restrict__ A,
                                                const short* __restrict__ W,
                                                const float* __restrict__ bias,
                                                short* __restrict__ C,
                                                int M, int N, int K) {
  __shared__ short As[64][72];
  __shared__ short Bs[64][72];
  int bm = blockIdx.y * 64, bn = blockIdx.x * 64;
  int tid = threadIdx.x, lane = tid & 63, wv = tid >> 6;
  int quad = lane >> 4, m16 = lane & 15;
  int wr = (wv >> 1) * 32, wc = (wv & 1) * 32;
  int srow = tid >> 2, scc = (tid & 3) * 16;
  const short* Ar = A + (size_t)(bm + srow) * K + scc;
  const short* Wr = W + (size_t)(bn + srow) * K + scc;
  f32x4 acc[2][2];
#pragma unroll
  for (int m = 0; m < 2; ++m)
#pragma unroll
    for (int n = 0; n < 2; ++n) acc[m][n] = (f32x4){0.f, 0.f, 0.f, 0.f};
  for (int k0 = 0; k0 < K; k0 += 64) {
    *(bf16x8*)&As[srow][scc] = *(const bf16x8*)&Ar[k0];
    *(bf16x8*)&As[srow][scc + 8] = *(const bf16x8*)&Ar[k0 + 8];
    *(bf16x8*)&Bs[srow][scc] = *(const bf16x8*)&Wr[k0];
    *(bf16x8*)&Bs[srow][scc + 8] = *(const bf16x8*)&Wr[k0 + 8];
    __syncthreads();
#pragma unroll
    for (int kk = 0; kk < 2; ++kk) {
      bf16x8 af[2], bf[2];
#pragma unroll
      for (int m = 0; m < 2; ++m) af[m] = *(const bf16x8*)&As[wr + m * 16 + m16][kk * 32 + quad * 8];
#pragma unroll
      for (int n = 0; n < 2; ++n) bf[n] = *(const bf16x8*)&Bs[wc + n * 16 + m16][kk * 32 + quad * 8];
#pragma unroll
      for (int m = 0; m < 2; ++m)
#pragma unroll
        for (int n = 0; n < 2; ++n)
          acc[m][n] = __builtin_amdgcn_mfma_f32_16x16x32_bf16(af[m], bf[n], acc[m][n], 0, 0, 0);
    }
    __syncthreads();
  }
#pragma unroll
  for (int n = 0; n < 2; ++n) {
    int col = bn + wc + n * 16 + m16;
    float b = bias[col];
#pragma unroll
    for (int m = 0; m < 2; ++m) {
      int row0 = bm + wr + m * 16 + quad * 4;
#pragma unroll
      for (int r = 0; r < 4; ++r) {
        float v = acc[m][n][r] + b;
        if (ACT) v = fmaxf(v, 0.f);
        C[(size_t)(row0 + r) * N + col] = f2bf(v);
      }
    }
  }
}

// ---------------- attn-out projection (full-row 32x256 block) + split-combine + add&LN ----------------
__global__ __launch_bounds__(256) void k_projln(const float* __restrict__ Opart,
                                                const float* __restrict__ Lpart,
                                                const short* __restrict__ W,
                                                const float* __restrict__ bias,
                                                short* __restrict__ h,
                                                const float* __restrict__ g,
                                                const float* __restrict__ b) {
  __shared__ short As[32][72];
  __shared__ short Bs[256][72];
  __shared__ float red[32][4];
  int bm = blockIdx.x * 32;
  int tid = threadIdx.x, lane = tid & 63, wv = tid >> 6;
  int quad = lane >> 4, m16 = lane & 15;
  int wc = wv * 64;
  int arow = tid >> 3, ac = (tid & 7) * 8;
  float invden[NH_];
#pragma unroll
  for (int hh = 0; hh < NH_; ++hh) {
    float dsum = 0.f;
#pragma unroll
    for (int sp = 0; sp < SPLITS_; ++sp)
      dsum += Lpart[(size_t)(sp * NH_ + hh) * S_ + bm + arow];
    invden[hh] = 1.0f / dsum;
  }
  f32x4 acc[2][4];
#pragma unroll
  for (int m = 0; m < 2; ++m)
#pragma unroll
    for (int n = 0; n < 4; ++n) acc[m][n] = (f32x4){0.f, 0.f, 0.f, 0.f};
#pragma unroll
  for (int k0 = 0; k0 < H_; k0 += 64) {
    {
      const int head = k0 >> 6;  // compile-time (loop unrolled)
      int rowA = bm + arow;
      float ns[8] = {0.f, 0.f, 0.f, 0.f, 0.f, 0.f, 0.f, 0.f};
#pragma unroll
      for (int sp = 0; sp < SPLITS_; ++sp) {
        const float* op = &Opart[((size_t)(sp * NH_ + head) * S_ + rowA) * 64 + ac];
        float4 u0 = *(const float4*)op;
        float4 u1 = *(const float4*)(op + 4);
        ns[0] += u0.x; ns[1] += u0.y; ns[2] += u0.z; ns[3] += u0.w;
        ns[4] += u1.x; ns[5] += u1.y; ns[6] += u1.z; ns[7] += u1.w;
      }
      float iv = invden[head];
      union { short s[8]; bf16x8 v; } o;
#pragma unroll
      for (int j = 0; j < 8; ++j) o.s[j] = f2bf(ns[j] * iv);
      *(bf16x8*)&As[arow][ac] = o.v;
    }
#pragma unroll
    for (int p = 0; p < 4; ++p) {
      int br = p * 64 + (tid >> 2), bc = (tid & 3) * 16;
      const short* wp = &W[(size_t)br * H_ + k0 + bc];
      *(bf16x8*)&Bs[br][bc] = *(const bf16x8*)&wp[0];
      *(bf16x8*)&Bs[br][bc + 8] = *(const bf16x8*)&wp[8];
    }
    __syncthreads();
#pragma unroll
    for (int kk = 0; kk < 2; ++kk) {
      bf16x8 af[2], bf[4];
#pragma unroll
      for (int m = 0; m < 2; ++m) af[m] = *(const bf16x8*)&As[m * 16 + m16][kk * 32 + quad * 8];
#pragma unroll
      for (int n = 0; n < 4; ++n) bf[n] = *(const bf16x8*)&Bs[wc + n * 16 + m16][kk * 32 + quad * 8];
#pragma unroll
      for (int m = 0; m < 2; ++m)
#pragma unroll
        for (int n = 0; n < 4; ++n)
          acc[m][n] = __builtin_amdgcn_mfma_f32_16x16x32_bf16(af[m], bf[n], acc[m][n], 0, 0, 0);
    }
    __syncthreads();
  }
  // ---- epilogue: x = h_old + (acc + bias); LN over full 256-col rows ----
  float bcol[4], gcol[4], bbcol[4];
  int col[4];
#pragma unroll
  for (int n = 0; n < 4; ++n) {
    col[n] = wc + n * 16 + m16;
    bcol[n] = bias[col[n]];
    gcol[n] = g[col[n]];
    bbcol[n] = b[col[n]];
  }
  float x[2][4][4];
#pragma unroll
  for (int m = 0; m < 2; ++m)
#pragma unroll
    for (int r = 0; r < 4; ++r) {
      int row = bm + m * 16 + quad * 4 + r;
#pragma unroll
      for (int n = 0; n < 4; ++n)
        x[m][n][r] = bf2f(h[(size_t)row * H_ + col[n]]) + acc[m][n][r] + bcol[n];
    }
#pragma unroll
  for (int m = 0; m < 2; ++m)
#pragma unroll
    for (int r = 0; r < 4; ++r) {
      float s = (x[m][0][r] + x[m][1][r]) + (x[m][2][r] + x[m][3][r]);
#pragma unroll
      for (int mask = 1; mask < 16; mask <<= 1) s += __shfl_xor(s, mask, 16);
      if (m16 == 0) red[m * 16 + quad * 4 + r][wv] = s;
    }
  __syncthreads();
  float mean[2][4];
#pragma unroll
  for (int m = 0; m < 2; ++m)
#pragma unroll
    for (int r = 0; r < 4; ++r) {
      int R = m * 16 + quad * 4 + r;
      mean[m][r] = (red[R][0] + red[R][1] + red[R][2] + red[R][3]) * (1.0f / H_);
    }
  __syncthreads();
#pragma unroll
  for (int m = 0; m < 2; ++m)
#pragma unroll
    for (int r = 0; r < 4; ++r) {
      float s = 0.f;
#pragma unroll
      for (int n = 0; n < 4; ++n) { float d = x[m][n][r] - mean[m][r]; s += d * d; }
#pragma unroll
      for (int mask = 1; mask < 16; mask <<= 1) s += __shfl_xor(s, mask, 16);
      if (m16 == 0) red[m * 16 + quad * 4 + r][wv] = s;
    }
  __syncthreads();
#pragma unroll
  for (int m = 0; m < 2; ++m)
#pragma unroll
    for (int r = 0; r < 4; ++r) {
      int R = m * 16 + quad * 4 + r;
      float var = (red[R][0] + red[R][1] + red[R][2] + red[R][3]) * (1.0f / H_);
      float inv = rsqrtf(var + EPS_);
      int row = bm + R;
#pragma unroll
      for (int n = 0; n < 4; ++n) {
        float v = (x[m][n][r] - mean[m][r]) * inv * gcol[n] + bbcol[n];
        h[(size_t)row * H_ + col[n]] = f2bf(v);
      }
    }
}

// ---------------- ff2 (full-row 32x256 block, runtime K) + add&LN ----------------
__global__ __launch_bounds__(256) void k_ff2ln(const short* __restrict__ A,
                                               const short* __restrict__ W,
                                               const float* __restrict__ bias,
                                               short* __restrict__ h,
                                               const float* __restrict__ g,
                                               const float* __restrict__ b,
                                               int K) {
  __shared__ short As[32][72];
  __shared__ short Bs[256][72];
  __shared__ float red[32][4];
  int bm = blockIdx.x * 32;
  int tid = threadIdx.x, lane = tid & 63, wv = tid >> 6;
  int quad = lane >> 4, m16 = lane & 15;
  int wc = wv * 64;
  int arow = tid >> 3, ac = (tid & 7) * 8;
  const short* Ar = A + (size_t)(bm + arow) * K + ac;
  f32x4 acc[2][4];
#pragma unroll
  for (int m = 0; m < 2; ++m)
#pragma unroll
    for (int n = 0; n < 4; ++n) acc[m][n] = (f32x4){0.f, 0.f, 0.f, 0.f};
  for (int k0 = 0; k0 < K; k0 += 64) {
    *(bf16x8*)&As[arow][ac] = *(const bf16x8*)&Ar[k0];
#pragma unroll
    for (int p = 0; p < 4; ++p) {
      int br = p * 64 + (tid >> 2), bc = (tid & 3) * 16;
      const short* wp = &W[(size_t)br * K + k0 + bc];
      *(bf16x8*)&Bs[br][bc] = *(const bf16x8*)&wp[0];
      *(bf16x8*)&Bs[br][bc + 8] = *(const bf16x8*)&wp[8];
    }
    __syncthreads();
#pragma unroll
    for (int kk = 0; kk < 2; ++kk) {
      bf16x8 af[2], bf[4];
#pragma unroll
      for (int m = 0; m < 2; ++m) af[m] = *(const bf16x8*)&As[m * 16 + m16][kk * 32 + quad * 8];
#pragma unroll
      for (int n = 0; n < 4; ++n) bf[n] = *(const bf16x8*)&Bs[wc + n * 16 + m16][kk * 32 + quad * 8];
#pragma unroll
      for (int m = 0; m < 2; ++m)
#pragma unroll
        for (int n = 0; n < 4; ++n)
          acc[m][n] = __builtin_amdgcn_mfma_f32_16x16x32_bf16(af[m], bf[n], acc[m][n], 0, 0, 0);
    }
    __syncthreads();
  }
  // ---- epilogue: x = h_old + (acc + bias); LN over full 256-col rows ----
  float bcol[4], gcol[4], bbcol[4];
  int col[4];
#pragma unroll
  for (int n = 0; n < 4; ++n) {
    col[n] = wc + n * 16 + m16;
    bcol[n] = bias[col[n]];
    gcol[n] = g[col[n]];
    bbcol[n] = b[col[n]];
  }
  float x[2][4][4];
#pragma unroll
  for (int m = 0; m < 2; ++m)
#pragma unroll
    for (int r = 0; r < 4; ++r) {
      int row = bm + m * 16 + quad * 4 + r;
#pragma unroll
      for (int n = 0; n < 4; ++n)
        x[m][n][r] = bf2f(h[(size_t)row * H_ + col[n]]) + acc[m][n][r] + bcol[n];
    }
#pragma unroll
  for (int m = 0; m < 2; ++m)
#pragma unroll
    for (int r = 0; r < 4; ++r) {
      float s = (x[m][0][r] + x[m][1][r]) + (x[m][2][r] + x[m][3][r]);
#pragma unroll
      for (int mask = 1; mask < 16; mask <<= 1) s += __shfl_xor(s, mask, 16);
      if (m16 == 0) red[m * 16 + quad * 4 + r][wv] = s;
    }
  __syncthreads();
  float mean[2][4];
#pragma unroll
  for (int m = 0; m < 2; ++m)
#pragma unroll
    for (int r = 0; r < 4; ++r) {
      int R = m * 16 + quad * 4 + r;
      mean[m][r] = (red[R][0] + red[R][1] + red[R][2] + red[R][3]) * (1.0f / H_);
    }
  __syncthreads();
#pragma unroll
  for (int m = 0; m < 2; ++m)
#pragma unroll
    for (int r = 0; r < 4; ++r) {
      float s = 0.f;
#pragma unroll
      for (int n = 0; n < 4; ++n) { float d = x[m][n][r] - mean[m][r]; s += d * d; }
#pragma unroll
      for (int mask = 1; mask < 16; mask <<= 1) s += __shfl_xor(s, mask, 16);
      if (m16 == 0) red[m * 16 + quad * 4 + r][wv] = s;
    }
  __syncthreads();
#pragma unroll
  for (int m = 0; m < 2; ++m)
#pragma unroll
    for (int r = 0; r < 4; ++r) {
      int R = m * 16 + quad * 4 + r;
      float var = (red[R][0] + red[R][1] + red[R][2] + red[R][3]) * (1.0f / H_);
      float inv = rsqrtf(var + EPS_);
      int row = bm + R;
#pragma unroll
      for (int n = 0; n < 4; ++n) {
        float v = (x[m][n][r] - mean[m][r]) * inv * gcol[n] + bbcol[n];
        h[(size_t)row * H_ + col[n]] = f2bf(v);
      }
    }
}

// ---------------- 32x64-tile, BK=64, runtime K (fc) ----------------
__global__ __launch_bounds__(256) void k_ff2(const short* __restrict__ A,
                                             const short* __restrict__ W,
                                             const float* __restrict__ bias,
                                             short* __restrict__ C, int K) {
  __shared__ short As[32][72];
  __shared__ short Bs[64][72];
  int bm = blockIdx.y * 32, bn = blockIdx.x * 64;
  int tid = threadIdx.x, lane = tid & 63, wv = tid >> 6;
  int quad = lane >> 4, m16 = lane & 15;
  int wr = (wv >> 1) * 16, wc = (wv & 1) * 32;
  int arow = tid >> 3, ac = (tid & 7) * 8;
  int brow = tid >> 2, bc = (tid & 3) * 16;
  const short* Ar = A + (size_t)(bm + arow) * K + ac;
  const short* Wr = W + (size_t)(bn + brow) * K + bc;
  f32x4 acc[2];
  acc[0] = (f32x4){0.f, 0.f, 0.f, 0.f};
  acc[1] = (f32x4){0.f, 0.f, 0.f, 0.f};
  for (int k0 = 0; k0 < K; k0 += 64) {
    *(bf16x8*)&As[arow][ac] = *(const bf16x8*)&Ar[k0];
    *(bf16x8*)&Bs[brow][bc] = *(const bf16x8*)&Wr[k0];
    *(bf16x8*)&Bs[brow][bc + 8] = *(const bf16x8*)&Wr[k0 + 8];
    __syncthreads();
    bf16x8 af0 = *(const bf16x8*)&As[wr + m16][quad * 8];
    bf16x8 af1 = *(const bf16x8*)&As[wr + m16][32 + quad * 8];
    bf16x8 b00 = *(const bf16x8*)&Bs[wc + m16][quad * 8];
    bf16x8 b01 = *(const bf16x8*)&Bs[wc + m16][32 + quad * 8];
    bf16x8 b10 = *(const bf16x8*)&Bs[wc + 16 + m16][quad * 8];
    bf16x8 b11 = *(const bf16x8*)&Bs[wc + 16 + m16][32 + quad * 8];
    acc[0] = __builtin_amdgcn_mfma_f32_16x16x32_bf16(af0, b00, acc[0], 0, 0, 0);
    acc[0] = __builtin_amdgcn_mfma_f32_16x16x32_bf16(af1, b01, acc[0], 0, 0, 0);
    acc[1] = __builtin_amdgcn_mfma_f32_16x16x32_bf16(af0, b10, acc[1], 0, 0, 0);
    acc[1] = __builtin_amdgcn_mfma_f32_16x16x32_bf16(af1, b11, acc[1], 0, 0, 0);
    __syncthreads();
  }
#pragma unroll
  for (int n = 0; n < 2; ++n) {
    int col = bn + wc + n * 16 + m16;
    float b = bias[col];
    int row0 = bm + wr + quad * 4;
#pragma unroll
    for (int r = 0; r < 4; ++r) {
      float v = acc[n][r] + b;
      C[(size_t)(row0 + r) * H_ + col] = f2bf(v);
    }
  }
}

// ---------------- MoE dual-expert 32x64 GEMM, fused gates ----------------
__global__ __launch_bounds__(256) void k_moe(const short* __restrict__ A,
                                             const short* __restrict__ EW,
                                             const float* __restrict__ EB,
                                             const float* __restrict__ gw,
                                             const float* __restrict__ gb,
                                             short* __restrict__ C,
                                             int N, int K) {
  __shared__ short As[32][40];
  __shared__ short B0s[64][40];
  __shared__ short B1s[64][40];
  __shared__ float sc_lds[32][NE_];
  __shared__ float g0_lds[NE_];
  __shared__ float vals_lds[32][2];
  __shared__ int sel_lds[2];
  int bm = blockIdx.y * 32, bn = blockIdx.x * 64;
  int tid = threadIdx.x, lane = tid & 63, wv = tid >> 6;
  int quad = lane >> 4, m16 = lane & 15;
  int wr = (wv >> 1) * 16, wc = (wv & 1) * 32;
  int srow = tid >> 2, sc = (tid & 3) * 8;
  // --- gates: block rows + token-0 (for sel), all in-block ---
  if (tid < 128) {
    int r = tid & 31, e = tid >> 5;
    const short* xs = A + (size_t)(bm + r) * K;
    const float* w = gw + (size_t)e * K;
    float acc = 0.f;
    for (int i = 0; i < K; i += 8) {
      bf16x8 xv = *(const bf16x8*)&xs[i];
      float4 w0 = *(const float4*)&w[i];
      float4 w1 = *(const float4*)&w[i + 4];
      acc += bf2f(xv[0]) * w0.x + bf2f(xv[1]) * w0.y + bf2f(xv[2]) * w0.z + bf2f(xv[3]) * w0.w;
      acc += bf2f(xv[4]) * w1.x + bf2f(xv[5]) * w1.y + bf2f(xv[6]) * w1.z + bf2f(xv[7]) * w1.w;
    }
    sc_lds[r][e] = acc + gb[e];
  } else if (tid < 132) {
    int e = tid - 128;
    const float* w = gw + (size_t)e * K;
    float acc = 0.f;
    for (int i = 0; i < K; i += 8) {
      bf16x8 xv = *(const bf16x8*)&A[i];
      float4 w0 = *(const float4*)&w[i];
      float4 w1 = *(const float4*)&w[i + 4];
      acc += bf2f(xv[0]) * w0.x + bf2f(xv[1]) * w0.y + bf2f(xv[2]) * w0.z + bf2f(xv[3]) * w0.w;
      acc += bf2f(xv[4]) * w1.x + bf2f(xv[5]) * w1.y + bf2f(xv[6]) * w1.z + bf2f(xv[7]) * w1.w;
    }
    g0_lds[e] = acc + gb[e];
  }
  __syncthreads();
  if (tid < 32) {
    float g[4];
#pragma unroll
    for (int e = 0; e < 4; ++e) g[e] = sc_lds[tid][e];
    float mx = fmaxf(fmaxf(g[0], g[1]), fmaxf(g[2], g[3]));
    float sum = 0.f;
#pragma unroll
    for (int e = 0; e < 4; ++e) { g[e] = __expf(g[e] - mx); sum += g[e]; }
    float inv = 1.0f / sum;
#pragma unroll
    for (int e = 0; e < 4; ++e) g[e] *= inv;
    int i0 = 0; float v0 = g[0];
#pragma unroll
    for (int e = 1; e < 4; ++e) if (g[e] > v0) { v0 = g[e]; i0 = e; }
    float v1 = -1.0f;
#pragma unroll
    for (int e = 0; e < 4; ++e) if (e != i0 && g[e] > v1) v1 = g[e];
    vals_lds[tid][0] = v0;
    vals_lds[tid][1] = v1;
  } else if (tid == 32) {
    float g[4];
#pragma unroll
    for (int e = 0; e < 4; ++e) g[e] = g0_lds[e];
    float mx = fmaxf(fmaxf(g[0], g[1]), fmaxf(g[2], g[3]));
    float sum = 0.f;
#pragma unroll
    for (int e = 0; e < 4; ++e) { g[e] = __expf(g[e] - mx); sum += g[e]; }
    float inv = 1.0f / sum;
#pragma unroll
    for (int e = 0; e < 4; ++e) g[e] *= inv;
    int i0 = 0; float v0 = g[0];
#pragma unroll
    for (int e = 1; e < 4; ++e) if (g[e] > v0) { v0 = g[e]; i0 = e; }
    int i1 = 0; float v1 = -1.0f;
#pragma unroll
    for (int e = 0; e < 4; ++e) if (e != i0 && g[e] > v1) { v1 = g[e]; i1 = e; }
    sel_lds[0] = i0;
    sel_lds[1] = i1;
  }
  __syncthreads();
  int e0 = sel_lds[0], e1 = sel_lds[1];
  const short* W0r = EW + (size_t)e0 * N * K + (size_t)(bn + srow) * K + sc;
  const short* W1r = EW + (size_t)e1 * N * K + (size_t)(bn + srow) * K + sc;
  const float* b0 = EB + (size_t)e0 * N;
  const float* b1 = EB + (size_t)e1 * N;
  const short* Ar = A + (size_t)(bm + (srow & 31)) * K + sc;
  f32x4 a0[2], a1[2];
  a0[0] = a0[1] = (f32x4){0.f, 0.f, 0.f, 0.f};
  a1[0] = a1[1] = (f32x4){0.f, 0.f, 0.f, 0.f};
  for (int k0 = 0; k0 < K; k0 += 32) {
    if (tid < 128) *(bf16x8*)&As[srow][sc] = *(const bf16x8*)&Ar[k0];
    *(bf16x8*)&B0s[srow][sc] = *(const bf16x8*)&W0r[k0];
    *(bf16x8*)&B1s[srow][sc] = *(const bf16x8*)&W1r[k0];
    __syncthreads();
    bf16x8 af = *(const bf16x8*)&As[wr + m16][quad * 8];
#pragma unroll
    for (int n = 0; n < 2; ++n) {
      bf16x8 bf0 = *(const bf16x8*)&B0s[wc + n * 16 + m16][quad * 8];
      bf16x8 bf1 = *(const bf16x8*)&B1s[wc + n * 16 + m16][quad * 8];
      a0[n] = __builtin_amdgcn_mfma_f32_16x16x32_bf16(af, bf0, a0[n], 0, 0, 0);
      a1[n] = __builtin_amdgcn_mfma_f32_16x16x32_bf16(af, bf1, a1[n], 0, 0, 0);
    }
    __syncthreads();
  }
#pragma unroll
  for (int n = 0; n < 2; ++n) {
    int col = bn + wc + n * 16 + m16;
    float bb0 = b0[col], bb1 = b1[col];
    int row0 = wr + quad * 4;
#pragma unroll
    for (int r = 0; r < 4; ++r) {
      int lrow = row0 + r;
      float v = vals_lds[lrow][0] * (a0[n][r] + bb0) + vals_lds[lrow][1] * (a1[n][r] + bb1);
      C[(size_t)(bm + lrow) * N + col] = f2bf(v);
    }
  }
}

// ---------------- 128x128-tile bf16 GEMM (ff1) ----------------
template <int ACT>
__global__ __launch_bounds__(256) void k_gemm128(const short* __restrict__ A,
                                                 const short* __restrict__ W,
                                                 const float* __restrict__ bias,
                                                 short* __restrict__ C,
                                                 int M, int N, int K) {
  __shared__ short As[128][40];
  __shared__ short Bs[128][40];
  int bm = blockIdx.y * 128, bn = blockIdx.x * 128;
  int tid = threadIdx.x, lane = tid & 63, wv = tid >> 6;
  int quad = lane >> 4, m16 = lane & 15;
  int wr = (wv >> 1) * 64, wc = (wv & 1) * 64;
  int srow = tid >> 1, sc = (tid & 1) * 16;
  const short* Ar = A + (size_t)(bm + srow) * K + sc;
  const short* Wr = W + (size_t)(bn + srow) * K + sc;
  f32x4 acc[4][4];
#pragma unroll
  for (int m = 0; m < 4; ++m)
#pragma unroll
    for (int n = 0; n < 4; ++n) acc[m][n] = (f32x4){0.f, 0.f, 0.f, 0.f};
  for (int k0 = 0; k0 < K; k0 += 32) {
    *(bf16x8*)&As[srow][sc] = *(const bf16x8*)&Ar[k0];
    *(bf16x8*)&As[srow][sc + 8] = *(const bf16x8*)&Ar[k0 + 8];
    *(bf16x8*)&Bs[srow][sc] = *(const bf16x8*)&Wr[k0];
    *(bf16x8*)&Bs[srow][sc + 8] = *(const bf16x8*)&Wr[k0 + 8];
    __syncthreads();
    bf16x8 af[4], bf[4];
#pragma unroll
    for (int m = 0; m < 4; ++m) af[m] = *(const bf16x8*)&As[wr + m * 16 + m16][quad * 8];
#pragma unroll
    for (int n = 0; n < 4; ++n) bf[n] = *(const bf16x8*)&Bs[wc + n * 16 + m16][quad * 8];
#pragma unroll
    for (int m = 0; m < 4; ++m)
#pragma unroll
      for (int n = 0; n < 4; ++n)
        acc[m][n] = __builtin_amdgcn_mfma_f32_16x16x32_bf16(af[m], bf[n], acc[m][n], 0, 0, 0);
    __syncthreads();
  }
#pragma unroll
  for (int n = 0; n < 4; ++n) {
    int col = bn + wc + n * 16 + m16;
    float b = bias[col];
#pragma unroll
    for (int m = 0; m < 4; ++m) {
      int row0 = bm + wr + m * 16 + quad * 4;
#pragma unroll
      for (int r = 0; r < 4; ++r) {
        float v = acc[m][n][r] + b;
        if (ACT) v = fmaxf(v, 0.f);
        C[(size_t)(row0 + r) * N + col] = f2bf(v);
      }
    }
  }
}

// ---------------- logits pass 1: GEMM -> per-row partial sums of exp only ----------------
__global__ __launch_bounds__(256) void k_gsum(const short* __restrict__ A,
                                              const short* __restrict__ W,
                                              const float* __restrict__ bias,
                                              float* __restrict__ psums,
                                              int M, int N, int K) {
  __shared__ short As[128][40];
  __shared__ short Bs[128][40];
  int bm = blockIdx.y * 128, bn = blockIdx.x * 128;
  int tid = threadIdx.x, lane = tid & 63, wv = tid >> 6;
  int quad = lane >> 4, m16 = lane & 15;
  int wr = (wv >> 1) * 64, wc = (wv & 1) * 64;
  int srow = tid >> 1, sc = (tid & 1) * 16;
  const short* Ar = A + (size_t)(bm + srow) * K + sc;
  int br = bn + srow;
  const short* Wr = W + (size_t)(br < N ? br : N - 1) * K + sc;
  f32x4 acc[4][4];
#pragma unroll
  for (int m = 0; m < 4; ++m)
#pragma unroll
    for (int n = 0; n < 4; ++n) acc[m][n] = (f32x4){0.f, 0.f, 0.f, 0.f};
  for (int k0 = 0; k0 < K; k0 += 32) {
    *(bf16x8*)&As[srow][sc] = *(const bf16x8*)&Ar[k0];
    *(bf16x8*)&As[srow][sc + 8] = *(const bf16x8*)&Ar[k0 + 8];
    *(bf16x8*)&Bs[srow][sc] = *(const bf16x8*)&Wr[k0];
    *(bf16x8*)&Bs[srow][sc + 8] = *(const bf16x8*)&Wr[k0 + 8];
    __syncthreads();
    bf16x8 af[4], bf[4];
#pragma unroll
    for (int m = 0; m < 4; ++m) af[m] = *(const bf16x8*)&As[wr + m * 16 + m16][quad * 8];
#pragma unroll
    for (int n = 0; n < 4; ++n) bf[n] = *(const bf16x8*)&Bs[wc + n * 16 + m16][quad * 8];
#pragma unroll
    for (int m = 0; m < 4; ++m)
#pragma unroll
      for (int n = 0; n < 4; ++n)
        acc[m][n] = __builtin_amdgcn_mfma_f32_16x16x32_bf16(af[m], bf[n], acc[m][n], 0, 0, 0);
    __syncthreads();
  }
  float bcol[4];
  int cvalid[4];
#pragma unroll
  for (int n = 0; n < 4; ++n) {
    int col = bn + wc + n * 16 + m16;
    cvalid[n] = (col < N);
    bcol[n] = cvalid[n] ? bias[col] : 0.f;
  }
  int pslot = blockIdx.x * 2 + (wv & 1);
#pragma unroll
  for (int m = 0; m < 4; ++m) {
#pragma unroll
    for (int r = 0; r < 4; ++r) {
      int row = bm + wr + m * 16 + quad * 4 + r;
      float es = 0.f;
#pragma unroll
      for (int n = 0; n < 4; ++n) {
        if (cvalid[n]) {
          float v = acc[m][n][r] + bcol[n];
          es += __expf(v);
        }
      }
#pragma unroll
      for (int mask = 1; mask < 16; mask <<= 1) es += __shfl_xor(es, mask, 16);
      if (m16 == 0) psums[(size_t)row * PSTRIDE_ + pslot] = es;
    }
  }
}

// ---------------- lse[row] = log(sum psums[row]) ----------------
__global__ __launch_bounds__(256) void k_lse(const float* __restrict__ psums,
                                             float* __restrict__ lse, int nslots) {
  int wv = threadIdx.x >> 6, lane = threadIdx.x & 63;
  int s = blockIdx.x * 4 + wv;
  float a = 0.f;
  for (int i = lane; i < nslots; i += 64) a += psums[(size_t)s * PSTRIDE_ + i];
#pragma unroll
  for (int mask = 1; mask < 64; mask <<= 1) a += __shfl_xor(a, mask, 64);
  if (lane == 0) lse[s] = logf(a);
}

// ---------------- logits pass 2: GEMM -> out = v - lse[row] ----------------
__global__ __launch_bounds__(256) void k_gout(const short* __restrict__ A,
                                              const short* __restrict__ W,
                                              const float* __restrict__ bias,
                                              const float* __restrict__ lse,
                                              float* __restrict__ C,
                                              int M, int N, int K) {
  __shared__ short As[128][40];
  __shared__ short Bs[128][40];
  int bm = blockIdx.y * 128, bn = blockIdx.x * 128;
  int tid = threadIdx.x, lane = tid & 63, wv = tid >> 6;
  int quad = lane >> 4, m16 = lane & 15;
  int wr = (wv >> 1) * 64, wc = (wv & 1) * 64;
  int srow = tid >> 1, sc = (tid & 1) * 16;
  const short* Ar = A + (size_t)(bm + srow) * K + sc;
  int br = bn + srow;
  const short* Wr = W + (size_t)(br < N ? br : N - 1) * K + sc;
  f32x4 acc[4][4];
#pragma unroll
  for (int m = 0; m < 4; ++m)
#pragma unroll
    for (int n = 0; n < 4; ++n) acc[m][n] = (f32x4){0.f, 0.f, 0.f, 0.f};
  for (int k0 = 0; k0 < K; k0 += 32) {
    *(bf16x8*)&As[srow][sc] = *(const bf16x8*)&Ar[k0];
    *(bf16x8*)&As[srow][sc + 8] = *(const bf16x8*)&Ar[k0 + 8];
    *(bf16x8*)&Bs[srow][sc] = *(const bf16x8*)&Wr[k0];
    *(bf16x8*)&Bs[srow][sc + 8] = *(const bf16x8*)&Wr[k0 + 8];
    __syncthreads();
    bf16x8 af[4], bf[4];
#pragma unroll
    for (int m = 0; m < 4; ++m) af[m] = *(const bf16x8*)&As[wr + m * 16 + m16][quad * 8];
#pragma unroll
    for (int n = 0; n < 4; ++n) bf[n] = *(const bf16x8*)&Bs[wc + n * 16 + m16][quad * 8];
#pragma unroll
    for (int m = 0; m < 4; ++m)
#pragma unroll
      for (int n = 0; n < 4; ++n)
        acc[m][n] = __builtin_amdgcn_mfma_f32_16x16x32_bf16(af[m], bf[n], acc[m][n], 0, 0, 0);
    __syncthreads();
  }
  float bcol[4];
  int cvalid[4];
#pragma unroll
  for (int n = 0; n < 4; ++n) {
    int col = bn + wc + n * 16 + m16;
    cvalid[n] = (col < N);
    bcol[n] = cvalid[n] ? bias[col] : 0.f;
  }
#pragma unroll
  for (int m = 0; m < 4; ++m) {
#pragma unroll
    for (int r = 0; r < 4; ++r) {
      int row = bm + wr + m * 16 + quad * 4 + r;
      float flse = lse[row];
#pragma unroll
      for (int n = 0; n < 4; ++n) {
        if (cvalid[n]) {
          float v = acc[m][n][r] + bcol[n] - flse;
          C[(size_t)row * N + (bn + wc + n * 16 + m16)] = v;
        }
      }
    }
  }
}

// ---------------- bf16-MFMA flash attention, KV-split, QBLK=128 ----------------
__global__ __launch_bounds__(256) void k_attn(const short* __restrict__ qkv,
                                              float* __restrict__ Opart,
                                              float* __restrict__ Lpart) {
  __shared__ short Ks[64][72];
  __shared__ short Vt[64][72];
  int tid = threadIdx.x, lane = tid & 63, wv = tid >> 6;
  int quad = lane >> 4, m16 = lane & 15;
  int head = blockIdx.y, hd0 = head * HD_;
  int split = blockIdx.z;
  int qbaseA = blockIdx.x * 128 + wv * 16;
  int qbaseB = qbaseA + 64;
  bf16x8 qfA[2], qfB[2];
  {
    const short* qrA = qkv + (size_t)(qbaseA + m16) * (3 * H_) + hd0 + quad * 8;
    qfA[0] = *(const bf16x8*)&qrA[0];
    qfA[1] = *(const bf16x8*)&qrA[32];
    const short* qrB = qkv + (size_t)(qbaseB + m16) * (3 * H_) + hd0 + quad * 8;
    qfB[0] = *(const bf16x8*)&qrB[0];
    qfB[1] = *(const bf16x8*)&qrB[32];
  }
  f32x4 oA[4], oB[4];
#pragma unroll
  for (int dt = 0; dt < 4; ++dt) {
    oA[dt] = (f32x4){0.f, 0.f, 0.f, 0.f};
    oB[dt] = (f32x4){0.f, 0.f, 0.f, 0.f};
  }
  float lA = 0.f, lB = 0.f;

  int kb_end = (split + 1) * (S_ / 64 / SPLITS_);
  for (int kb = split * (S_ / 64 / SPLITS_); kb < kb_end; ++kb) {
    __syncthreads();
    {
      int key = tid >> 2, d0 = (tid & 3) * 16;
      const short* kr = qkv + (size_t)(kb * 64 + key) * (3 * H_) + H_ + hd0 + d0;
      *(bf16x8*)&Ks[key][d0] = *(const bf16x8*)&kr[0];
      *(bf16x8*)&Ks[key][d0 + 8] = *(const bf16x8*)&kr[8];
    }
    {
      int key0 = (tid & 15) * 4, d0 = (tid >> 4) * 4;
      const short* vbase = qkv + (size_t)(kb * 64 + key0) * (3 * H_) + 2 * H_ + hd0 + d0;
      short4 v0 = *(const short4*)&vbase[0];
      short4 v1 = *(const short4*)&vbase[3 * H_];
      short4 v2 = *(const short4*)&vbase[6 * H_];
      short4 v3 = *(const short4*)&vbase[9 * H_];
      short4 t0 = {v0.x, v1.x, v2.x, v3.x};
      short4 t1 = {v0.y, v1.y, v2.y, v3.y};
      short4 t2 = {v0.z, v1.z, v2.z, v3.z};
      short4 t3 = {v0.w, v1.w, v2.w, v3.w};
      *(short4*)&Vt[d0 + 0][key0] = t0;
      *(short4*)&Vt[d0 + 1][key0] = t1;
      *(short4*)&Vt[d0 + 2][key0] = t2;
      *(short4*)&Vt[d0 + 3][key0] = t3;
    }
    __syncthreads();
    f32x4 sA[4], sB[4];
#pragma unroll
    for (int kt = 0; kt < 4; ++kt) {
      bf16x8 ak0 = *(const bf16x8*)&Ks[kt * 16 + m16][quad * 8];
      bf16x8 ak1 = *(const bf16x8*)&Ks[kt * 16 + m16][32 + quad * 8];
      f32x4 zA = (f32x4){0.f, 0.f, 0.f, 0.f};
      zA = __builtin_amdgcn_mfma_f32_16x16x32_bf16(ak0, qfA[0], zA, 0, 0, 0);
      zA = __builtin_amdgcn_mfma_f32_16x16x32_bf16(ak1, qfA[1], zA, 0, 0, 0);
      sA[kt] = zA;
      f32x4 zB = (f32x4){0.f, 0.f, 0.f, 0.f};
      zB = __builtin_amdgcn_mfma_f32_16x16x32_bf16(ak0, qfB[0], zB, 0, 0, 0);
      zB = __builtin_amdgcn_mfma_f32_16x16x32_bf16(ak1, qfB[1], zB, 0, 0, 0);
      sB[kt] = zB;
    }
    unsigned pwA[4][2], pwB[4][2];
    {
      float rsum = 0.f;
#pragma unroll
      for (int kt = 0; kt < 4; ++kt) {
        float p0 = __expf(sA[kt][0] * SCALE_);
        float p1 = __expf(sA[kt][1] * SCALE_);
        float p2 = __expf(sA[kt][2] * SCALE_);
        float p3 = __expf(sA[kt][3] * SCALE_);
        rsum += (p0 + p1) + (p2 + p3);
        asm("v_cvt_pk_bf16_f32 %0, %1, %2" : "=v"(pwA[kt][0]) : "v"(p0), "v"(p1));
        asm("v_cvt_pk_bf16_f32 %0, %1, %2" : "=v"(pwA[kt][1]) : "v"(p2), "v"(p3));
      }
      unsigned ua = __builtin_bit_cast(unsigned, rsum), ub = ua;
      asm volatile("v_permlane16_swap_b32 %0, %1" : "+v"(ua), "+v"(ub));
      float s01 = __builtin_bit_cast(float, ua) + __builtin_bit_cast(float, ub);
      unsigned uc = __builtin_bit_cast(unsigned, s01), ud = uc;
      asm volatile("v_permlane32_swap_b32 %0, %1" : "+v"(uc), "+v"(ud));
      lA += __builtin_bit_cast(float, uc) + __builtin_bit_cast(float, ud);
    }
    {
      float rsum = 0.f;
#pragma unroll
      for (int kt = 0; kt < 4; ++kt) {
        float p0 = __expf(sB[kt][0] * SCALE_);
        float p1 = __expf(sB[kt][1] * SCALE_);
        float p2 = __expf(sB[kt][2] * SCALE_);
        float p3 = __expf(sB[kt][3] * SCALE_);
        rsum += (p0 + p1) + (p2 + p3);
        asm("v_cvt_pk_bf16_f32 %0, %1, %2" : "=v"(pwB[kt][0]) : "v"(p0), "v"(p1));
        asm("v_cvt_pk_bf16_f32 %0, %1, %2" : "=v"(pwB[kt][1]) : "v"(p2), "v"(p3));
      }
      unsigned ua = __builtin_bit_cast(unsigned, rsum), ub = ua;
      asm volatile("v_permlane16_swap_b32 %0, %1" : "+v"(ua), "+v"(ub));
      float s01 = __builtin_bit_cast(float, ua) + __builtin_bit_cast(float, ub);
      unsigned uc = __builtin_bit_cast(unsigned, s01), ud = uc;
      asm volatile("v_permlane32_swap_b32 %0, %1" : "+v"(uc), "+v"(ud));
      lB += __builtin_bit_cast(float, uc) + __builtin_bit_cast(float, ud);
    }
#pragma unroll
    for (int c = 0; c < 2; ++c) {
      unsigned a0 = pwA[2 * c][0], b0 = pwA[2 * c + 1][0];
      asm volatile("v_permlane32_swap_b32 %0, %1" : "+v"(a0), "+v"(b0));
      asm volatile("v_permlane16_swap_b32 %0, %1" : "+v"(a0), "+v"(b0));
      unsigned a1 = pwA[2 * c][1], b1 = pwA[2 * c + 1][1];
      asm volatile("v_permlane32_swap_b32 %0, %1" : "+v"(a1), "+v"(b1));
      asm volatile("v_permlane16_swap_b32 %0, %1" : "+v"(a1), "+v"(b1));
      union { unsigned u[4]; bf16x8 v; } puA;
      puA.u[0] = a0; puA.u[1] = a1; puA.u[2] = b0; puA.u[3] = b1;
      bf16x8 paA = puA.v;
      unsigned c0 = pwB[2 * c][0], d0w = pwB[2 * c + 1][0];
      asm volatile("v_permlane32_swap_b32 %0, %1" : "+v"(c0), "+v"(d0w));
      asm volatile("v_permlane16_swap_b32 %0, %1" : "+v"(c0), "+v"(d0w));
      unsigned c1 = pwB[2 * c][1], d1w = pwB[2 * c + 1][1];
      asm volatile("v_permlane32_swap_b32 %0, %1" : "+v"(c1), "+v"(d1w));
      asm volatile("v_permlane16_swap_b32 %0, %1" : "+v"(c1), "+v"(d1w));
      union { unsigned u[4]; bf16x8 v; } puB;
      puB.u[0] = c0; puB.u[1] = c1; puB.u[2] = d0w; puB.u[3] = d1w;
      bf16x8 paB = puB.v;
#pragma unroll
      for (int dt = 0; dt < 4; ++dt) {
        bf16x8 bv = *(const bf16x8*)&Vt[dt * 16 + m16][c * 32 + quad * 8];
        oA[dt] = __builtin_amdgcn_mfma_f32_16x16x32_bf16(paA, bv, oA[dt], 0, 0, 0);
        oB[dt] = __builtin_amdgcn_mfma_f32_16x16x32_bf16(paB, bv, oB[dt], 0, 0, 0);
      }
    }
  }
  float* Op = Opart + ((size_t)(split * NH_ + head) * S_) * 64;
#pragma unroll
  for (int dt = 0; dt < 4; ++dt) {
#pragma unroll
    for (int r = 0; r < 4; ++r) {
      int rowA = qbaseA + quad * 4 + r;
      Op[(size_t)rowA * 64 + dt * 16 + m16] = oA[dt][r];
      int rowB = qbaseB + quad * 4 + r;
      Op[(size_t)rowB * 64 + dt * 16 + m16] = oB[dt][r];
    }
  }
  if (quad == 0) {
    float* Lp = Lpart + (size_t)(split * NH_ + head) * S_;
    Lp[qbaseA + m16] = lA;
    Lp[qbaseB + m16] = lB;
  }
}

extern "C" void kernel_launch(void* const* d_in, const int* in_sizes, int n_in,
                              void* d_out, int out_size, void* d_ws, size_t ws_size,
                              hipStream_t stream) {
  const int* x = (const int*)d_in[0];
  const float* emb = (const float*)d_in[1];
  const float* moe_gw[3] = {(const float*)d_in[2], (const float*)d_in[6], (const float*)d_in[10]};
  const float* moe_gb[3] = {(const float*)d_in[3], (const float*)d_in[7], (const float*)d_in[11]};
  const float* moe_eb[3] = {(const float*)d_in[5], (const float*)d_in[9], (const float*)d_in[13]};
  const float* attn_in_b = (const float*)d_in[15];
  const float* attn_out_b = (const float*)d_in[17];
  const float* ln1_g = (const float*)d_in[18];
  const float* ln1_b = (const float*)d_in[19];
  const float* ln2_g = (const float*)d_in[20];
  const float* ln2_b = (const float*)d_in[21];
  const float* ff1_b = (const float*)d_in[23];
  const float* ff2_b = (const float*)d_in[25];
  const float* fc_b = (const float*)d_in[27];
  const float* out_b = (const float*)d_in[29];
  float* out = (float*)d_out;

  short* wsS = (short*)d_ws;
  size_t off = 0;
  auto alloc = [&](size_t n) { short* p = wsS + off; off += n; return p; };
  short* ewb0 = alloc(131072);
  short* ewb1 = alloc(262144);
  short* ewb2 = alloc(262144);
  short* aiwb = alloc(393216);
  short* aowb = alloc(131072);
  short* f1wb = alloc(1048576);   // after layers: psums+lse alias f1wb+f2wb (4 MB >= 2.64 MB)
  short* f2wb = alloc(1048576);
  short* fcwb = alloc(65536);
  short* owb  = alloc(2560000);
  short* hb_e = alloc((size_t)S_ * E_);
  short* hb_a = alloc((size_t)S_ * H_);
  short* hb_b = alloc((size_t)S_ * H_);
  short* qkvb = alloc((size_t)S_ * 3 * H_);
  short* abufb = alloc((size_t)S_ * H_);     // (retained, unused)
  short* tmpb = alloc((size_t)S_ * H_);      // aliased as Lpart during attention; fc output
  short* ffhb = alloc((size_t)S_ * FF_);     // aliased as Opart during attention
  float* Opart = (float*)ffhb;
  float* Lpart = (float*)tmpb;
  float* psums = (float*)f1wb;               // used only after all layers done
  float* lse = psums + (size_t)S_ * PSTRIDE_;

  const short* moe_ewb[3] = {ewb0, ewb1, ewb2};

  CvtArgs ca;
  ca.src[0] = (const float*)d_in[4];  ca.dst[0] = ewb0;
  ca.src[1] = (const float*)d_in[8];  ca.dst[1] = ewb1;
  ca.src[2] = (const float*)d_in[12]; ca.dst[2] = ewb2;
  ca.src[3] = (const float*)d_in[14]; ca.dst[3] = aiwb;
  ca.src[4] = (const float*)d_in[16]; ca.dst[4] = aowb;
  ca.src[5] = (const float*)d_in[22]; ca.dst[5] = f1wb;
  ca.src[6] = (const float*)d_in[24]; ca.dst[6] = f2wb;
  ca.src[7] = (const float*)d_in[26]; ca.dst[7] = fcwb;
  ca.src[8] = (const float*)d_in[28]; ca.dst[8] = owb;
  int sizes[9] = {131072, 262144, 262144, 393216, 131072, 1048576, 1048576, 65536, 2560000};
  ca.pfx[0] = 0;
  for (int i = 0; i < 9; ++i) ca.pfx[i + 1] = ca.pfx[i] + sizes[i] / 2048;
  k_cvt<<<dim3(ca.pfx[9] + S_ * E_ / 2048), dim3(256), 0, stream>>>(ca, x, emb, hb_e);

  const short* moe_in[3] = {hb_e, hb_a, hb_b};
  short* moe_out[3] = {hb_a, hb_b, hb_a};
  int moe_k[3] = {E_, H_, H_};
  for (int i = 0; i < 3; ++i) {
    k_moe<<<dim3(H_ / 64, S_ / 32), dim3(256), 0, stream>>>(
        moe_in[i], moe_ewb[i], moe_eb[i], moe_gw[i], moe_gb[i], moe_out[i], H_, moe_k[i]);
  }

  for (int l = 0; l < NL_; ++l) {
    k_gemm64<0><<<dim3(3 * H_ / 64, S_ / 64), dim3(256), 0, stream>>>(
        hb_a, aiwb + (size_t)l * 3 * H_ * H_, attn_in_b + (size_t)l * 3 * H_, qkvb, S_, 3 * H_, H_);
    k_attn<<<dim3(S_ / 128, NH_, SPLITS_), dim3(256), 0, stream>>>(qkvb, Opart, Lpart);
    k_projln<<<dim3(S_ / 32), dim3(256), 0, stream>>>(
        Opart, Lpart, aowb + (size_t)l * H_ * H_, attn_out_b + (size_t)l * H_,
        hb_a, ln1_g + l * H_, ln1_b + l * H_);
    k_gemm128<1><<<dim3(FF_ / 128, S_ / 128), dim3(256), 0, stream>>>(
        hb_a, f1wb + (size_t)l * FF_ * H_, ff1_b + (size_t)l * FF_, ffhb, S_, FF_, H_);
    k_ff2ln<<<dim3(S_ / 32), dim3(256), 0, stream>>>(
        ffhb, f2wb + (size_t)l * H_ * FF_, ff2_b + (size_t)l * H_,
        hb_a, ln2_g + l * H_, ln2_b + l * H_, FF_);
  }

  k_ff2<<<dim3(H_ / 64, S_ / 32), dim3(256), 0, stream>>>(hb_a, fcwb, fc_b, tmpb, H_);
  int nxb = (V_ + 127) / 128;  // 79
  k_gsum<<<dim3(nxb, S_ / 128), dim3(256), 0, stream>>>(tmpb, owb, out_b, psums, S_, V_, H_);
  k_lse<<<dim3(S_ / 4), dim3(256), 0, stream>>>(psums, lse, nxb * 2);
  k_gout<<<dim3(nxb, S_ / 128), dim3(256), 0, stream>>>(tmpb, owb, out_b, lse, out, S_, V_, H_);
}

// Round 7
// 576.184 us; speedup vs baseline: 1.0431x; 1.0431x over previous
//
#include <hip/hip_runtime.h>
#include <math.h>

#define S_ 4096
#define V_ 10000
#define E_ 128
#define H_ 256
#define NE_ 4
#define NH_ 4
#define HD_ 64
#define FF_ 2048
#define NL_ 2
#define EPS_ 1e-5f
#define SCALE_ 0.125f
#define SPLITS_ 4
#define PSTRIDE_ 160   // 79 col-blocks * 2 wave-halves = 158, padded

typedef __attribute__((ext_vector_type(8))) short bf16x8;
typedef __attribute__((ext_vector_type(4))) float f32x4;

static __device__ __forceinline__ short f2bf(float f) {
  unsigned u = __builtin_bit_cast(unsigned, f);
  unsigned r = (u + 0x7fffu + ((u >> 16) & 1u)) >> 16;
  return (short)r;
}
static __device__ __forceinline__ float bf2f(short s) {
  unsigned u = ((unsigned)(unsigned short)s) << 16;
  return __builtin_bit_cast(float, u);
}

// XCD-aware bijective block swizzle (T1). Requires nwg % 8 == 0 (all call
// sites satisfy this). Remaps hw dispatch id -> logical (bx, by) such that
// each XCD gets a contiguous bx-range (B-panel chunks stay in its L2).
static __device__ __forceinline__ int2 xcd_swz() {
  int gx = gridDim.x, gy = gridDim.y;
  int nwg = gx * gy;
  int b0 = blockIdx.y * gx + blockIdx.x;
  int wg = (b0 & 7) * (nwg >> 3) + (b0 >> 3);
  int2 r;
  r.x = wg / gy;  // logical col-block (B chunk)
  r.y = wg % gy;  // logical row-block
  return r;
}

// ---------------- weight fp32 -> bf16 pre-convert + embedding gather ----------------
struct CvtArgs {
  const float* src[9];
  short* dst[9];
  int pfx[10];
};
__global__ __launch_bounds__(256) void k_cvt(CvtArgs a, const int* __restrict__ x,
                                             const float* __restrict__ emb,
                                             short* __restrict__ h) {
  int b = blockIdx.x;
  if (b >= a.pfx[9]) {
    int i8 = (b - a.pfx[9]) * 2048 + threadIdx.x * 8;
    int s = i8 >> 7, e = i8 & 127;
    const float* sp = &emb[(size_t)x[s] * E_ + e];
    float4 v0 = *(const float4*)sp;
    float4 v1 = *(const float4*)(sp + 4);
    short4 o0, o1;
    o0.x = f2bf(v0.x); o0.y = f2bf(v0.y); o0.z = f2bf(v0.z); o0.w = f2bf(v0.w);
    o1.x = f2bf(v1.x); o1.y = f2bf(v1.y); o1.z = f2bf(v1.z); o1.w = f2bf(v1.w);
    *(short4*)&h[i8] = o0;
    *(short4*)&h[i8 + 4] = o1;
    return;
  }
  int s = 0;
  while (b >= a.pfx[s + 1]) ++s;
  size_t base = (size_t)(b - a.pfx[s]) * 2048 + threadIdx.x * 8;
  const float* sp = a.src[s] + base;
  short* dp = a.dst[s] + base;
  float4 v0 = *(const float4*)sp;
  float4 v1 = *(const float4*)(sp + 4);
  short4 o0, o1;
  o0.x = f2bf(v0.x); o0.y = f2bf(v0.y); o0.z = f2bf(v0.z); o0.w = f2bf(v0.w);
  o1.x = f2bf(v1.x); o1.y = f2bf(v1.y); o1.z = f2bf(v1.z); o1.w = f2bf(v1.w);
  *(short4*)dp = o0;
  *(short4*)(dp + 4) = o1;
}

// ---------------- 64x64-tile bf16 GEMM, BK=64 (qkv) ----------------
template <int ACT>
__global__ __launch_bounds__(256) void k_gemm64(const short* __restrict__ A,
                                                const short* __restrict__ W,
                                                const float* __restrict__ bias,
                                                short* __restrict__ C,
                                                int M, int N, int K) {
  __shared__ short As[64][72];
  __shared__ short Bs[64][72];
  int2 bxy = xcd_swz();
  int bm = bxy.y * 64, bn = bxy.x * 64;
  int tid = threadIdx.x, lane = tid & 63, wv = tid >> 6;
  int quad = lane >> 4, m16 = lane & 15;
  int wr = (wv >> 1) * 32, wc = (wv & 1) * 32;
  int srow = tid >> 2, scc = (tid & 3) * 16;
  const short* Ar = A + (size_t)(bm + srow) * K + scc;
  const short* Wr = W + (size_t)(bn + srow) * K + scc;
  f32x4 acc[2][2];
#pragma unroll
  for (int m = 0; m < 2; ++m)
#pragma unroll
    for (int n = 0; n < 2; ++n) acc[m][n] = (f32x4){0.f, 0.f, 0.f, 0.f};
  for (int k0 = 0; k0 < K; k0 += 64) {
    *(bf16x8*)&As[srow][scc] = *(const bf16x8*)&Ar[k0];
    *(bf16x8*)&As[srow][scc + 8] = *(const bf16x8*)&Ar[k0 + 8];
    *(bf16x8*)&Bs[srow][scc] = *(const bf16x8*)&Wr[k0];
    *(bf16x8*)&Bs[srow][scc + 8] = *(const bf16x8*)&Wr[k0 + 8];
    __syncthreads();
#pragma unroll
    for (int kk = 0; kk < 2; ++kk) {
      bf16x8 af[2], bf[2];
#pragma unroll
      for (int m = 0; m < 2; ++m) af[m] = *(const bf16x8*)&As[wr + m * 16 + m16][kk * 32 + quad * 8];
#pragma unroll
      for (int n = 0; n < 2; ++n) bf[n] = *(const bf16x8*)&Bs[wc + n * 16 + m16][kk * 32 + quad * 8];
#pragma unroll
      for (int m = 0; m < 2; ++m)
#pragma unroll
        for (int n = 0; n < 2; ++n)
          acc[m][n] = __builtin_amdgcn_mfma_f32_16x16x32_bf16(af[m], bf[n], acc[m][n], 0, 0, 0);
    }
    __syncthreads();
  }
#pragma unroll
  for (int n = 0; n < 2; ++n) {
    int col = bn + wc + n * 16 + m16;
    float b = bias[col];
#pragma unroll
    for (int m = 0; m < 2; ++m) {
      int row0 = bm + wr + m * 16 + quad * 4;
#pragma unroll
      for (int r = 0; r < 4; ++r) {
        float v = acc[m][n][r] + b;
        if (ACT) v = fmaxf(v, 0.f);
        C[(size_t)(row0 + r) * N + col] = f2bf(v);
      }
    }
  }
}

// ---------------- attn-out projection with fused split-combine ----------------
__global__ __launch_bounds__(256) void k_proj(const float* __restrict__ Opart,
                                              const float* __restrict__ Lpart,
                                              const short* __restrict__ W,
                                              const float* __restrict__ bias,
                                              short* __restrict__ C) {
  __shared__ short As[32][40];
  __shared__ short Bs[64][40];
  int bm = blockIdx.y * 32, bn = blockIdx.x * 64;
  int tid = threadIdx.x, lane = tid & 63, wv = tid >> 6;
  int quad = lane >> 4, m16 = lane & 15;
  int wr = (wv >> 1) * 16, wc = (wv & 1) * 32;
  int srow = tid >> 2, sc = (tid & 3) * 8;
  int rowA = bm + (srow & 31);
  const short* Wr = W + (size_t)(bn + srow) * H_ + sc;
  float invden[NH_];
  if (tid < 128) {
#pragma unroll
    for (int hh = 0; hh < NH_; ++hh) {
      float dsum = 0.f;
#pragma unroll
      for (int sp = 0; sp < SPLITS_; ++sp)
        dsum += Lpart[(size_t)(sp * NH_ + hh) * S_ + rowA];
      invden[hh] = 1.0f / dsum;
    }
  }
  f32x4 acc[2];
  acc[0] = (f32x4){0.f, 0.f, 0.f, 0.f};
  acc[1] = (f32x4){0.f, 0.f, 0.f, 0.f};
#pragma unroll
  for (int k0 = 0; k0 < H_; k0 += 32) {
    if (tid < 128) {
      const int head = k0 >> 6;            // compile-time (sc < 32)
      int dd = (k0 & 63) + sc;
      float n0 = 0.f, n1 = 0.f, n2 = 0.f, n3 = 0.f, n4 = 0.f, n5 = 0.f, n6 = 0.f, n7 = 0.f;
#pragma unroll
      for (int sp = 0; sp < SPLITS_; ++sp) {
        const float* op = &Opart[((size_t)(sp * NH_ + head) * S_ + rowA) * 64 + dd];
        float4 u0 = *(const float4*)op;
        float4 u1 = *(const float4*)(op + 4);
        n0 += u0.x; n1 += u0.y; n2 += u0.z; n3 += u0.w;
        n4 += u1.x; n5 += u1.y; n6 += u1.z; n7 += u1.w;
      }
      float iv = invden[head];
      union { short s[8]; bf16x8 v; } o;
      o.s[0] = f2bf(n0 * iv); o.s[1] = f2bf(n1 * iv);
      o.s[2] = f2bf(n2 * iv); o.s[3] = f2bf(n3 * iv);
      o.s[4] = f2bf(n4 * iv); o.s[5] = f2bf(n5 * iv);
      o.s[6] = f2bf(n6 * iv); o.s[7] = f2bf(n7 * iv);
      *(bf16x8*)&As[srow][sc] = o.v;
    }
    *(bf16x8*)&Bs[srow][sc] = *(const bf16x8*)&Wr[k0];
    __syncthreads();
    bf16x8 af = *(const bf16x8*)&As[wr + m16][quad * 8];
    bf16x8 bf0 = *(const bf16x8*)&Bs[wc + m16][quad * 8];
    bf16x8 bf1 = *(const bf16x8*)&Bs[wc + 16 + m16][quad * 8];
    acc[0] = __builtin_amdgcn_mfma_f32_16x16x32_bf16(af, bf0, acc[0], 0, 0, 0);
    acc[1] = __builtin_amdgcn_mfma_f32_16x16x32_bf16(af, bf1, acc[1], 0, 0, 0);
    __syncthreads();
  }
#pragma unroll
  for (int n = 0; n < 2; ++n) {
    int col = bn + wc + n * 16 + m16;
    float b = bias[col];
    int row0 = bm + wr + quad * 4;
#pragma unroll
    for (int r = 0; r < 4; ++r) {
      float v = acc[n][r] + b;
      C[(size_t)(row0 + r) * H_ + col] = f2bf(v);
    }
  }
}

// ---------------- 32x64-tile, BK=64, runtime K (ff2, fc) ----------------
__global__ __launch_bounds__(256) void k_ff2(const short* __restrict__ A,
                                             const short* __restrict__ W,
                                             const float* __restrict__ bias,
                                             short* __restrict__ C, int K) {
  __shared__ short As[32][72];
  __shared__ short Bs[64][72];
  int bm = blockIdx.y * 32, bn = blockIdx.x * 64;
  int tid = threadIdx.x, lane = tid & 63, wv = tid >> 6;
  int quad = lane >> 4, m16 = lane & 15;
  int wr = (wv >> 1) * 16, wc = (wv & 1) * 32;
  int arow = tid >> 3, ac = (tid & 7) * 8;
  int brow = tid >> 2, bc = (tid & 3) * 16;
  const short* Ar = A + (size_t)(bm + arow) * K + ac;
  const short* Wr = W + (size_t)(bn + brow) * K + bc;
  f32x4 acc[2];
  acc[0] = (f32x4){0.f, 0.f, 0.f, 0.f};
  acc[1] = (f32x4){0.f, 0.f, 0.f, 0.f};
  for (int k0 = 0; k0 < K; k0 += 64) {
    *(bf16x8*)&As[arow][ac] = *(const bf16x8*)&Ar[k0];
    *(bf16x8*)&Bs[brow][bc] = *(const bf16x8*)&Wr[k0];
    *(bf16x8*)&Bs[brow][bc + 8] = *(const bf16x8*)&Wr[k0 + 8];
    __syncthreads();
    bf16x8 af0 = *(const bf16x8*)&As[wr + m16][quad * 8];
    bf16x8 af1 = *(const bf16x8*)&As[wr + m16][32 + quad * 8];
    bf16x8 b00 = *(const bf16x8*)&Bs[wc + m16][quad * 8];
    bf16x8 b01 = *(const bf16x8*)&Bs[wc + m16][32 + quad * 8];
    bf16x8 b10 = *(const bf16x8*)&Bs[wc + 16 + m16][quad * 8];
    bf16x8 b11 = *(const bf16x8*)&Bs[wc + 16 + m16][32 + quad * 8];
    acc[0] = __builtin_amdgcn_mfma_f32_16x16x32_bf16(af0, b00, acc[0], 0, 0, 0);
    acc[0] = __builtin_amdgcn_mfma_f32_16x16x32_bf16(af1, b01, acc[0], 0, 0, 0);
    acc[1] = __builtin_amdgcn_mfma_f32_16x16x32_bf16(af0, b10, acc[1], 0, 0, 0);
    acc[1] = __builtin_amdgcn_mfma_f32_16x16x32_bf16(af1, b11, acc[1], 0, 0, 0);
    __syncthreads();
  }
#pragma unroll
  for (int n = 0; n < 2; ++n) {
    int col = bn + wc + n * 16 + m16;
    float b = bias[col];
    int row0 = bm + wr + quad * 4;
#pragma unroll
    for (int r = 0; r < 4; ++r) {
      float v = acc[n][r] + b;
      C[(size_t)(row0 + r) * H_ + col] = f2bf(v);
    }
  }
}

// ---------------- MoE dual-expert 32x64 GEMM, fused gates ----------------
__global__ __launch_bounds__(256) void k_moe(const short* __restrict__ A,
                                             const short* __restrict__ EW,
                                             const float* __restrict__ EB,
                                             const float* __restrict__ gw,
                                             const float* __restrict__ gb,
                                             short* __restrict__ C,
                                             int N, int K) {
  __shared__ short As[32][40];
  __shared__ short B0s[64][40];
  __shared__ short B1s[64][40];
  __shared__ float sc_lds[32][NE_];
  __shared__ float g0_lds[NE_];
  __shared__ float vals_lds[32][2];
  __shared__ int sel_lds[2];
  int bm = blockIdx.y * 32, bn = blockIdx.x * 64;
  int tid = threadIdx.x, lane = tid & 63, wv = tid >> 6;
  int quad = lane >> 4, m16 = lane & 15;
  int wr = (wv >> 1) * 16, wc = (wv & 1) * 32;
  int srow = tid >> 2, sc = (tid & 3) * 8;
  // --- gates: block rows + token-0 (for sel), all in-block ---
  if (tid < 128) {
    int r = tid & 31, e = tid >> 5;
    const short* xs = A + (size_t)(bm + r) * K;
    const float* w = gw + (size_t)e * K;
    float acc = 0.f;
    for (int i = 0; i < K; i += 8) {
      bf16x8 xv = *(const bf16x8*)&xs[i];
      float4 w0 = *(const float4*)&w[i];
      float4 w1 = *(const float4*)&w[i + 4];
      acc += bf2f(xv[0]) * w0.x + bf2f(xv[1]) * w0.y + bf2f(xv[2]) * w0.z + bf2f(xv[3]) * w0.w;
      acc += bf2f(xv[4]) * w1.x + bf2f(xv[5]) * w1.y + bf2f(xv[6]) * w1.z + bf2f(xv[7]) * w1.w;
    }
    sc_lds[r][e] = acc + gb[e];
  } else if (tid < 132) {
    int e = tid - 128;
    const float* w = gw + (size_t)e * K;
    float acc = 0.f;
    for (int i = 0; i < K; i += 8) {
      bf16x8 xv = *(const bf16x8*)&A[i];
      float4 w0 = *(const float4*)&w[i];
      float4 w1 = *(const float4*)&w[i + 4];
      acc += bf2f(xv[0]) * w0.x + bf2f(xv[1]) * w0.y + bf2f(xv[2]) * w0.z + bf2f(xv[3]) * w0.w;
      acc += bf2f(xv[4]) * w1.x + bf2f(xv[5]) * w1.y + bf2f(xv[6]) * w1.z + bf2f(xv[7]) * w1.w;
    }
    g0_lds[e] = acc + gb[e];
  }
  __syncthreads();
  if (tid < 32) {
    float g[4];
#pragma unroll
    for (int e = 0; e < 4; ++e) g[e] = sc_lds[tid][e];
    float mx = fmaxf(fmaxf(g[0], g[1]), fmaxf(g[2], g[3]));
    float sum = 0.f;
#pragma unroll
    for (int e = 0; e < 4; ++e) { g[e] = __expf(g[e] - mx); sum += g[e]; }
    float inv = 1.0f / sum;
#pragma unroll
    for (int e = 0; e < 4; ++e) g[e] *= inv;
    int i0 = 0; float v0 = g[0];
#pragma unroll
    for (int e = 1; e < 4; ++e) if (g[e] > v0) { v0 = g[e]; i0 = e; }
    float v1 = -1.0f;
#pragma unroll
    for (int e = 0; e < 4; ++e) if (e != i0 && g[e] > v1) v1 = g[e];
    vals_lds[tid][0] = v0;
    vals_lds[tid][1] = v1;
  } else if (tid == 32) {
    float g[4];
#pragma unroll
    for (int e = 0; e < 4; ++e) g[e] = g0_lds[e];
    float mx = fmaxf(fmaxf(g[0], g[1]), fmaxf(g[2], g[3]));
    float sum = 0.f;
#pragma unroll
    for (int e = 0; e < 4; ++e) { g[e] = __expf(g[e] - mx); sum += g[e]; }
    float inv = 1.0f / sum;
#pragma unroll
    for (int e = 0; e < 4; ++e) g[e] *= inv;
    int i0 = 0; float v0 = g[0];
#pragma unroll
    for (int e = 1; e < 4; ++e) if (g[e] > v0) { v0 = g[e]; i0 = e; }
    int i1 = 0; float v1 = -1.0f;
#pragma unroll
    for (int e = 0; e < 4; ++e) if (e != i0 && g[e] > v1) { v1 = g[e]; i1 = e; }
    sel_lds[0] = i0;
    sel_lds[1] = i1;
  }
  __syncthreads();
  int e0 = sel_lds[0], e1 = sel_lds[1];
  const short* W0r = EW + (size_t)e0 * N * K + (size_t)(bn + srow) * K + sc;
  const short* W1r = EW + (size_t)e1 * N * K + (size_t)(bn + srow) * K + sc;
  const float* b0 = EB + (size_t)e0 * N;
  const float* b1 = EB + (size_t)e1 * N;
  const short* Ar = A + (size_t)(bm + (srow & 31)) * K + sc;
  f32x4 a0[2], a1[2];
  a0[0] = a0[1] = (f32x4){0.f, 0.f, 0.f, 0.f};
  a1[0] = a1[1] = (f32x4){0.f, 0.f, 0.f, 0.f};
  for (int k0 = 0; k0 < K; k0 += 32) {
    if (tid < 128) *(bf16x8*)&As[srow][sc] = *(const bf16x8*)&Ar[k0];
    *(bf16x8*)&B0s[srow][sc] = *(const bf16x8*)&W0r[k0];
    *(bf16x8*)&B1s[srow][sc] = *(const bf16x8*)&W1r[k0];
    __syncthreads();
    bf16x8 af = *(const bf16x8*)&As[wr + m16][quad * 8];
#pragma unroll
    for (int n = 0; n < 2; ++n) {
      bf16x8 bf0 = *(const bf16x8*)&B0s[wc + n * 16 + m16][quad * 8];
      bf16x8 bf1 = *(const bf16x8*)&B1s[wc + n * 16 + m16][quad * 8];
      a0[n] = __builtin_amdgcn_mfma_f32_16x16x32_bf16(af, bf0, a0[n], 0, 0, 0);
      a1[n] = __builtin_amdgcn_mfma_f32_16x16x32_bf16(af, bf1, a1[n], 0, 0, 0);
    }
    __syncthreads();
  }
#pragma unroll
  for (int n = 0; n < 2; ++n) {
    int col = bn + wc + n * 16 + m16;
    float bb0 = b0[col], bb1 = b1[col];
    int row0 = wr + quad * 4;
#pragma unroll
    for (int r = 0; r < 4; ++r) {
      int lrow = row0 + r;
      float v = vals_lds[lrow][0] * (a0[n][r] + bb0) + vals_lds[lrow][1] * (a1[n][r] + bb1);
      C[(size_t)(bm + lrow) * N + col] = f2bf(v);
    }
  }
}

// ---------------- 128x128-tile bf16 GEMM (ff1) ----------------
template <int ACT>
__global__ __launch_bounds__(256) void k_gemm128(const short* __restrict__ A,
                                                 const short* __restrict__ W,
                                                 const float* __restrict__ bias,
                                                 short* __restrict__ C,
                                                 int M, int N, int K) {
  __shared__ short As[128][40];
  __shared__ short Bs[128][40];
  int2 bxy = xcd_swz();
  int bm = bxy.y * 128, bn = bxy.x * 128;
  int tid = threadIdx.x, lane = tid & 63, wv = tid >> 6;
  int quad = lane >> 4, m16 = lane & 15;
  int wr = (wv >> 1) * 64, wc = (wv & 1) * 64;
  int srow = tid >> 1, sc = (tid & 1) * 16;
  const short* Ar = A + (size_t)(bm + srow) * K + sc;
  const short* Wr = W + (size_t)(bn + srow) * K + sc;
  f32x4 acc[4][4];
#pragma unroll
  for (int m = 0; m < 4; ++m)
#pragma unroll
    for (int n = 0; n < 4; ++n) acc[m][n] = (f32x4){0.f, 0.f, 0.f, 0.f};
  for (int k0 = 0; k0 < K; k0 += 32) {
    *(bf16x8*)&As[srow][sc] = *(const bf16x8*)&Ar[k0];
    *(bf16x8*)&As[srow][sc + 8] = *(const bf16x8*)&Ar[k0 + 8];
    *(bf16x8*)&Bs[srow][sc] = *(const bf16x8*)&Wr[k0];
    *(bf16x8*)&Bs[srow][sc + 8] = *(const bf16x8*)&Wr[k0 + 8];
    __syncthreads();
    bf16x8 af[4], bf[4];
#pragma unroll
    for (int m = 0; m < 4; ++m) af[m] = *(const bf16x8*)&As[wr + m * 16 + m16][quad * 8];
#pragma unroll
    for (int n = 0; n < 4; ++n) bf[n] = *(const bf16x8*)&Bs[wc + n * 16 + m16][quad * 8];
#pragma unroll
    for (int m = 0; m < 4; ++m)
#pragma unroll
      for (int n = 0; n < 4; ++n)
        acc[m][n] = __builtin_amdgcn_mfma_f32_16x16x32_bf16(af[m], bf[n], acc[m][n], 0, 0, 0);
    __syncthreads();
  }
#pragma unroll
  for (int n = 0; n < 4; ++n) {
    int col = bn + wc + n * 16 + m16;
    float b = bias[col];
#pragma unroll
    for (int m = 0; m < 4; ++m) {
      int row0 = bm + wr + m * 16 + quad * 4;
#pragma unroll
      for (int r = 0; r < 4; ++r) {
        float v = acc[m][n][r] + b;
        if (ACT) v = fmaxf(v, 0.f);
        C[(size_t)(row0 + r) * N + col] = f2bf(v);
      }
    }
  }
}

// ---------------- logits pass 1: GEMM -> per-row partial sums of exp only ----------------
__global__ __launch_bounds__(256) void k_gsum(const short* __restrict__ A,
                                              const short* __restrict__ W,
                                              const float* __restrict__ bias,
                                              float* __restrict__ psums,
                                              int M, int N, int K) {
  __shared__ short As[128][40];
  __shared__ short Bs[128][40];
  int2 bxy = xcd_swz();
  int bm = bxy.y * 128, bn = bxy.x * 128;
  int tid = threadIdx.x, lane = tid & 63, wv = tid >> 6;
  int quad = lane >> 4, m16 = lane & 15;
  int wr = (wv >> 1) * 64, wc = (wv & 1) * 64;
  int srow = tid >> 1, sc = (tid & 1) * 16;
  const short* Ar = A + (size_t)(bm + srow) * K + sc;
  int br = bn + srow;
  const short* Wr = W + (size_t)(br < N ? br : N - 1) * K + sc;
  f32x4 acc[4][4];
#pragma unroll
  for (int m = 0; m < 4; ++m)
#pragma unroll
    for (int n = 0; n < 4; ++n) acc[m][n] = (f32x4){0.f, 0.f, 0.f, 0.f};
  for (int k0 = 0; k0 < K; k0 += 32) {
    *(bf16x8*)&As[srow][sc] = *(const bf16x8*)&Ar[k0];
    *(bf16x8*)&As[srow][sc + 8] = *(const bf16x8*)&Ar[k0 + 8];
    *(bf16x8*)&Bs[srow][sc] = *(const bf16x8*)&Wr[k0];
    *(bf16x8*)&Bs[srow][sc + 8] = *(const bf16x8*)&Wr[k0 + 8];
    __syncthreads();
    bf16x8 af[4], bf[4];
#pragma unroll
    for (int m = 0; m < 4; ++m) af[m] = *(const bf16x8*)&As[wr + m * 16 + m16][quad * 8];
#pragma unroll
    for (int n = 0; n < 4; ++n) bf[n] = *(const bf16x8*)&Bs[wc + n * 16 + m16][quad * 8];
#pragma unroll
    for (int m = 0; m < 4; ++m)
#pragma unroll
      for (int n = 0; n < 4; ++n)
        acc[m][n] = __builtin_amdgcn_mfma_f32_16x16x32_bf16(af[m], bf[n], acc[m][n], 0, 0, 0);
    __syncthreads();
  }
  float bcol[4];
  int cvalid[4];
#pragma unroll
  for (int n = 0; n < 4; ++n) {
    int col = bn + wc + n * 16 + m16;
    cvalid[n] = (col < N);
    bcol[n] = cvalid[n] ? bias[col] : 0.f;
  }
  int pslot = bxy.x * 2 + (wv & 1);
#pragma unroll
  for (int m = 0; m < 4; ++m) {
#pragma unroll
    for (int r = 0; r < 4; ++r) {
      int row = bm + wr + m * 16 + quad * 4 + r;
      float es = 0.f;
#pragma unroll
      for (int n = 0; n < 4; ++n) {
        if (cvalid[n]) {
          float v = acc[m][n][r] + bcol[n];
          es += __expf(v);
        }
      }
#pragma unroll
      for (int mask = 1; mask < 16; mask <<= 1) es += __shfl_xor(es, mask, 16);
      if (m16 == 0) psums[(size_t)row * PSTRIDE_ + pslot] = es;
    }
  }
}

// ---------------- lse[row] = log(sum psums[row]) ----------------
__global__ __launch_bounds__(256) void k_lse(const float* __restrict__ psums,
                                             float* __restrict__ lse, int nslots) {
  int wv = threadIdx.x >> 6, lane = threadIdx.x & 63;
  int s = blockIdx.x * 4 + wv;
  float a = 0.f;
  for (int i = lane; i < nslots; i += 64) a += psums[(size_t)s * PSTRIDE_ + i];
#pragma unroll
  for (int mask = 1; mask < 64; mask <<= 1) a += __shfl_xor(a, mask, 64);
  if (lane == 0) lse[s] = logf(a);
}

// ---------------- logits pass 2: GEMM -> out = v - lse[row] ----------------
__global__ __launch_bounds__(256) void k_gout(const short* __restrict__ A,
                                              const short* __restrict__ W,
                                              const float* __restrict__ bias,
                                              const float* __restrict__ lse,
                                              float* __restrict__ C,
                                              int M, int N, int K) {
  __shared__ short As[128][40];
  __shared__ short Bs[128][40];
  int2 bxy = xcd_swz();
  int bm = bxy.y * 128, bn = bxy.x * 128;
  int tid = threadIdx.x, lane = tid & 63, wv = tid >> 6;
  int quad = lane >> 4, m16 = lane & 15;
  int wr = (wv >> 1) * 64, wc = (wv & 1) * 64;
  int srow = tid >> 1, sc = (tid & 1) * 16;
  const short* Ar = A + (size_t)(bm + srow) * K + sc;
  int br = bn + srow;
  const short* Wr = W + (size_t)(br < N ? br : N - 1) * K + sc;
  f32x4 acc[4][4];
#pragma unroll
  for (int m = 0; m < 4; ++m)
#pragma unroll
    for (int n = 0; n < 4; ++n) acc[m][n] = (f32x4){0.f, 0.f, 0.f, 0.f};
  for (int k0 = 0; k0 < K; k0 += 32) {
    *(bf16x8*)&As[srow][sc] = *(const bf16x8*)&Ar[k0];
    *(bf16x8*)&As[srow][sc + 8] = *(const bf16x8*)&Ar[k0 + 8];
    *(bf16x8*)&Bs[srow][sc] = *(const bf16x8*)&Wr[k0];
    *(bf16x8*)&Bs[srow][sc + 8] = *(const bf16x8*)&Wr[k0 + 8];
    __syncthreads();
    bf16x8 af[4], bf[4];
#pragma unroll
    for (int m = 0; m < 4; ++m) af[m] = *(const bf16x8*)&As[wr + m * 16 + m16][quad * 8];
#pragma unroll
    for (int n = 0; n < 4; ++n) bf[n] = *(const bf16x8*)&Bs[wc + n * 16 + m16][quad * 8];
#pragma unroll
    for (int m = 0; m < 4; ++m)
#pragma unroll
      for (int n = 0; n < 4; ++n)
        acc[m][n] = __builtin_amdgcn_mfma_f32_16x16x32_bf16(af[m], bf[n], acc[m][n], 0, 0, 0);
    __syncthreads();
  }
  float bcol[4];
  int cvalid[4];
#pragma unroll
  for (int n = 0; n < 4; ++n) {
    int col = bn + wc + n * 16 + m16;
    cvalid[n] = (col < N);
    bcol[n] = cvalid[n] ? bias[col] : 0.f;
  }
#pragma unroll
  for (int m = 0; m < 4; ++m) {
#pragma unroll
    for (int r = 0; r < 4; ++r) {
      int row = bm + wr + m * 16 + quad * 4 + r;
      float flse = lse[row];
#pragma unroll
      for (int n = 0; n < 4; ++n) {
        if (cvalid[n]) {
          float v = acc[m][n][r] + bcol[n] - flse;
          C[(size_t)row * N + (bn + wc + n * 16 + m16)] = v;
        }
      }
    }
  }
}

// ---------------- bf16-MFMA flash attention, KV-split, QBLK=128 ----------------
__global__ __launch_bounds__(256) void k_attn(const short* __restrict__ qkv,
                                              float* __restrict__ Opart,
                                              float* __restrict__ Lpart) {
  __shared__ short Ks[64][72];
  __shared__ short Vt[64][72];
  int tid = threadIdx.x, lane = tid & 63, wv = tid >> 6;
  int quad = lane >> 4, m16 = lane & 15;
  int head = blockIdx.y, hd0 = head * HD_;
  int split = blockIdx.z;
  int qbaseA = blockIdx.x * 128 + wv * 16;
  int qbaseB = qbaseA + 64;
  bf16x8 qfA[2], qfB[2];
  {
    const short* qrA = qkv + (size_t)(qbaseA + m16) * (3 * H_) + hd0 + quad * 8;
    qfA[0] = *(const bf16x8*)&qrA[0];
    qfA[1] = *(const bf16x8*)&qrA[32];
    const short* qrB = qkv + (size_t)(qbaseB + m16) * (3 * H_) + hd0 + quad * 8;
    qfB[0] = *(const bf16x8*)&qrB[0];
    qfB[1] = *(const bf16x8*)&qrB[32];
  }
  f32x4 oA[4], oB[4];
#pragma unroll
  for (int dt = 0; dt < 4; ++dt) {
    oA[dt] = (f32x4){0.f, 0.f, 0.f, 0.f};
    oB[dt] = (f32x4){0.f, 0.f, 0.f, 0.f};
  }
  float lA = 0.f, lB = 0.f;

  int kb_end = (split + 1) * (S_ / 64 / SPLITS_);
  for (int kb = split * (S_ / 64 / SPLITS_); kb < kb_end; ++kb) {
    __syncthreads();
    {
      int key = tid >> 2, d0 = (tid & 3) * 16;
      const short* kr = qkv + (size_t)(kb * 64 + key) * (3 * H_) + H_ + hd0 + d0;
      *(bf16x8*)&Ks[key][d0] = *(const bf16x8*)&kr[0];
      *(bf16x8*)&Ks[key][d0 + 8] = *(const bf16x8*)&kr[8];
    }
    {
      int key0 = (tid & 15) * 4, d0 = (tid >> 4) * 4;
      const short* vbase = qkv + (size_t)(kb * 64 + key0) * (3 * H_) + 2 * H_ + hd0 + d0;
      short4 v0 = *(const short4*)&vbase[0];
      short4 v1 = *(const short4*)&vbase[3 * H_];
      short4 v2 = *(const short4*)&vbase[6 * H_];
      short4 v3 = *(const short4*)&vbase[9 * H_];
      short4 t0 = {v0.x, v1.x, v2.x, v3.x};
      short4 t1 = {v0.y, v1.y, v2.y, v3.y};
      short4 t2 = {v0.z, v1.z, v2.z, v3.z};
      short4 t3 = {v0.w, v1.w, v2.w, v3.w};
      *(short4*)&Vt[d0 + 0][key0] = t0;
      *(short4*)&Vt[d0 + 1][key0] = t1;
      *(short4*)&Vt[d0 + 2][key0] = t2;
      *(short4*)&Vt[d0 + 3][key0] = t3;
    }
    __syncthreads();
    f32x4 sA[4], sB[4];
#pragma unroll
    for (int kt = 0; kt < 4; ++kt) {
      bf16x8 ak0 = *(const bf16x8*)&Ks[kt * 16 + m16][quad * 8];
      bf16x8 ak1 = *(const bf16x8*)&Ks[kt * 16 + m16][32 + quad * 8];
      f32x4 zA = (f32x4){0.f, 0.f, 0.f, 0.f};
      zA = __builtin_amdgcn_mfma_f32_16x16x32_bf16(ak0, qfA[0], zA, 0, 0, 0);
      zA = __builtin_amdgcn_mfma_f32_16x16x32_bf16(ak1, qfA[1], zA, 0, 0, 0);
      sA[kt] = zA;
      f32x4 zB = (f32x4){0.f, 0.f, 0.f, 0.f};
      zB = __builtin_amdgcn_mfma_f32_16x16x32_bf16(ak0, qfB[0], zB, 0, 0, 0);
      zB = __builtin_amdgcn_mfma_f32_16x16x32_bf16(ak1, qfB[1], zB, 0, 0, 0);
      sB[kt] = zB;
    }
    unsigned pwA[4][2], pwB[4][2];
    {
      float rsum = 0.f;
#pragma unroll
      for (int kt = 0; kt < 4; ++kt) {
        float p0 = __expf(sA[kt][0] * SCALE_);
        float p1 = __expf(sA[kt][1] * SCALE_);
        float p2 = __expf(sA[kt][2] * SCALE_);
        float p3 = __expf(sA[kt][3] * SCALE_);
        rsum += (p0 + p1) + (p2 + p3);
        asm("v_cvt_pk_bf16_f32 %0, %1, %2" : "=v"(pwA[kt][0]) : "v"(p0), "v"(p1));
        asm("v_cvt_pk_bf16_f32 %0, %1, %2" : "=v"(pwA[kt][1]) : "v"(p2), "v"(p3));
      }
      unsigned ua = __builtin_bit_cast(unsigned, rsum), ub = ua;
      asm volatile("v_permlane16_swap_b32 %0, %1" : "+v"(ua), "+v"(ub));
      float s01 = __builtin_bit_cast(float, ua) + __builtin_bit_cast(float, ub);
      unsigned uc = __builtin_bit_cast(unsigned, s01), ud = uc;
      asm volatile("v_permlane32_swap_b32 %0, %1" : "+v"(uc), "+v"(ud));
      lA += __builtin_bit_cast(float, uc) + __builtin_bit_cast(float, ud);
    }
    {
      float rsum = 0.f;
#pragma unroll
      for (int kt = 0; kt < 4; ++kt) {
        float p0 = __expf(sB[kt][0] * SCALE_);
        float p1 = __expf(sB[kt][1] * SCALE_);
        float p2 = __expf(sB[kt][2] * SCALE_);
        float p3 = __expf(sB[kt][3] * SCALE_);
        rsum += (p0 + p1) + (p2 + p3);
        asm("v_cvt_pk_bf16_f32 %0, %1, %2" : "=v"(pwB[kt][0]) : "v"(p0), "v"(p1));
        asm("v_cvt_pk_bf16_f32 %0, %1, %2" : "=v"(pwB[kt][1]) : "v"(p2), "v"(p3));
      }
      unsigned ua = __builtin_bit_cast(unsigned, rsum), ub = ua;
      asm volatile("v_permlane16_swap_b32 %0, %1" : "+v"(ua), "+v"(ub));
      float s01 = __builtin_bit_cast(float, ua) + __builtin_bit_cast(float, ub);
      unsigned uc = __builtin_bit_cast(unsigned, s01), ud = uc;
      asm volatile("v_permlane32_swap_b32 %0, %1" : "+v"(uc), "+v"(ud));
      lB += __builtin_bit_cast(float, uc) + __builtin_bit_cast(float, ud);
    }
#pragma unroll
    for (int c = 0; c < 2; ++c) {
      unsigned a0 = pwA[2 * c][0], b0 = pwA[2 * c + 1][0];
      asm volatile("v_permlane32_swap_b32 %0, %1" : "+v"(a0), "+v"(b0));
      asm volatile("v_permlane16_swap_b32 %0, %1" : "+v"(a0), "+v"(b0));
      unsigned a1 = pwA[2 * c][1], b1 = pwA[2 * c + 1][1];
      asm volatile("v_permlane32_swap_b32 %0, %1" : "+v"(a1), "+v"(b1));
      asm volatile("v_permlane16_swap_b32 %0, %1" : "+v"(a1), "+v"(b1));
      union { unsigned u[4]; bf16x8 v; } puA;
      puA.u[0] = a0; puA.u[1] = a1; puA.u[2] = b0; puA.u[3] = b1;
      bf16x8 paA = puA.v;
      unsigned c0 = pwB[2 * c][0], d0w = pwB[2 * c + 1][0];
      asm volatile("v_permlane32_swap_b32 %0, %1" : "+v"(c0), "+v"(d0w));
      asm volatile("v_permlane16_swap_b32 %0, %1" : "+v"(c0), "+v"(d0w));
      unsigned c1 = pwB[2 * c][1], d1w = pwB[2 * c + 1][1];
      asm volatile("v_permlane32_swap_b32 %0, %1" : "+v"(c1), "+v"(d1w));
      asm volatile("v_permlane16_swap_b32 %0, %1" : "+v"(c1), "+v"(d1w));
      union { unsigned u[4]; bf16x8 v; } puB;
      puB.u[0] = c0; puB.u[1] = c1; puB.u[2] = d0w; puB.u[3] = d1w;
      bf16x8 paB = puB.v;
#pragma unroll
      for (int dt = 0; dt < 4; ++dt) {
        bf16x8 bv = *(const bf16x8*)&Vt[dt * 16 + m16][c * 32 + quad * 8];
        oA[dt] = __builtin_amdgcn_mfma_f32_16x16x32_bf16(paA, bv, oA[dt], 0, 0, 0);
        oB[dt] = __builtin_amdgcn_mfma_f32_16x16x32_bf16(paB, bv, oB[dt], 0, 0, 0);
      }
    }
  }
  float* Op = Opart + ((size_t)(split * NH_ + head) * S_) * 64;
#pragma unroll
  for (int dt = 0; dt < 4; ++dt) {
#pragma unroll
    for (int r = 0; r < 4; ++r) {
      int rowA = qbaseA + quad * 4 + r;
      Op[(size_t)rowA * 64 + dt * 16 + m16] = oA[dt][r];
      int rowB = qbaseB + quad * 4 + r;
      Op[(size_t)rowB * 64 + dt * 16 + m16] = oB[dt][r];
    }
  }
  if (quad == 0) {
    float* Lp = Lpart + (size_t)(split * NH_ + head) * S_;
    Lp[qbaseA + m16] = lA;
    Lp[qbaseB + m16] = lB;
  }
}

// ---------------- h = LN(h + t) * g + b, wave-per-row ----------------
__global__ __launch_bounds__(256) void k_add_ln(short* __restrict__ h,
                                                const short* __restrict__ t_,
                                                const float* __restrict__ g,
                                                const float* __restrict__ b) {
  int wv = threadIdx.x >> 6, lane = threadIdx.x & 63;
  int s = blockIdx.x * 4 + wv;
  size_t off = (size_t)s * H_ + lane * 4;
  short4 hv = *(const short4*)&h[off];
  short4 tv = *(const short4*)&t_[off];
  float x[4] = {bf2f(hv.x) + bf2f(tv.x), bf2f(hv.y) + bf2f(tv.y),
                bf2f(hv.z) + bf2f(tv.z), bf2f(hv.w) + bf2f(tv.w)};
  float sum = x[0] + x[1] + x[2] + x[3];
#pragma unroll
  for (int mask = 1; mask < 64; mask <<= 1) sum += __shfl_xor(sum, mask, 64);
  float mean = sum * (1.0f / H_);
  float d[4], vs = 0.f;
#pragma unroll
  for (int i = 0; i < 4; ++i) { d[i] = x[i] - mean; vs += d[i] * d[i]; }
#pragma unroll
  for (int mask = 1; mask < 64; mask <<= 1) vs += __shfl_xor(vs, mask, 64);
  float inv = rsqrtf(vs * (1.0f / H_) + EPS_);
  float4 gv = *(const float4*)&g[lane * 4];
  float4 bv = *(const float4*)&b[lane * 4];
  short4 ov;
  ov.x = f2bf(d[0] * inv * gv.x + bv.x);
  ov.y = f2bf(d[1] * inv * gv.y + bv.y);
  ov.z = f2bf(d[2] * inv * gv.z + bv.z);
  ov.w = f2bf(d[3] * inv * gv.w + bv.w);
  *(short4*)&h[off] = ov;
}

extern "C" void kernel_launch(void* const* d_in, const int* in_sizes, int n_in,
                              void* d_out, int out_size, void* d_ws, size_t ws_size,
                              hipStream_t stream) {
  const int* x = (const int*)d_in[0];
  const float* emb = (const float*)d_in[1];
  const float* moe_gw[3] = {(const float*)d_in[2], (const float*)d_in[6], (const float*)d_in[10]};
  const float* moe_gb[3] = {(const float*)d_in[3], (const float*)d_in[7], (const float*)d_in[11]};
  const float* moe_eb[3] = {(const float*)d_in[5], (const float*)d_in[9], (const float*)d_in[13]};
  const float* attn_in_b = (const float*)d_in[15];
  const float* attn_out_b = (const float*)d_in[17];
  const float* ln1_g = (const float*)d_in[18];
  const float* ln1_b = (const float*)d_in[19];
  const float* ln2_g = (const float*)d_in[20];
  const float* ln2_b = (const float*)d_in[21];
  const float* ff1_b = (const float*)d_in[23];
  const float* ff2_b = (const float*)d_in[25];
  const float* fc_b = (const float*)d_in[27];
  const float* out_b = (const float*)d_in[29];
  float* out = (float*)d_out;

  short* wsS = (short*)d_ws;
  size_t off = 0;
  auto alloc = [&](size_t n) { short* p = wsS + off; off += n; return p; };
  short* ewb0 = alloc(131072);
  short* ewb1 = alloc(262144);
  short* ewb2 = alloc(262144);
  short* aiwb = alloc(393216);
  short* aowb = alloc(131072);
  short* f1wb = alloc(1048576);   // after layers: psums+lse alias f1wb+f2wb (4 MB >= 2.64 MB)
  short* f2wb = alloc(1048576);
  short* fcwb = alloc(65536);
  short* owb  = alloc(2560000);
  short* hb_e = alloc((size_t)S_ * E_);
  short* hb_a = alloc((size_t)S_ * H_);
  short* hb_b = alloc((size_t)S_ * H_);
  short* qkvb = alloc((size_t)S_ * 3 * H_);
  short* abufb = alloc((size_t)S_ * H_);     // (retained, unused)
  short* tmpb = alloc((size_t)S_ * H_);      // aliased as Lpart during attention; fc output
  short* ffhb = alloc((size_t)S_ * FF_);     // aliased as Opart during attention
  float* Opart = (float*)ffhb;
  float* Lpart = (float*)tmpb;
  float* psums = (float*)f1wb;               // used only after all layers done
  float* lse = psums + (size_t)S_ * PSTRIDE_;

  const short* moe_ewb[3] = {ewb0, ewb1, ewb2};

  CvtArgs ca;
  ca.src[0] = (const float*)d_in[4];  ca.dst[0] = ewb0;
  ca.src[1] = (const float*)d_in[8];  ca.dst[1] = ewb1;
  ca.src[2] = (const float*)d_in[12]; ca.dst[2] = ewb2;
  ca.src[3] = (const float*)d_in[14]; ca.dst[3] = aiwb;
  ca.src[4] = (const float*)d_in[16]; ca.dst[4] = aowb;
  ca.src[5] = (const float*)d_in[22]; ca.dst[5] = f1wb;
  ca.src[6] = (const float*)d_in[24]; ca.dst[6] = f2wb;
  ca.src[7] = (const float*)d_in[26]; ca.dst[7] = fcwb;
  ca.src[8] = (const float*)d_in[28]; ca.dst[8] = owb;
  int sizes[9] = {131072, 262144, 262144, 393216, 131072, 1048576, 1048576, 65536, 2560000};
  ca.pfx[0] = 0;
  for (int i = 0; i < 9; ++i) ca.pfx[i + 1] = ca.pfx[i] + sizes[i] / 2048;
  k_cvt<<<dim3(ca.pfx[9] + S_ * E_ / 2048), dim3(256), 0, stream>>>(ca, x, emb, hb_e);

  const short* moe_in[3] = {hb_e, hb_a, hb_b};
  short* moe_out[3] = {hb_a, hb_b, hb_a};
  int moe_k[3] = {E_, H_, H_};
  for (int i = 0; i < 3; ++i) {
    k_moe<<<dim3(H_ / 64, S_ / 32), dim3(256), 0, stream>>>(
        moe_in[i], moe_ewb[i], moe_eb[i], moe_gw[i], moe_gb[i], moe_out[i], H_, moe_k[i]);
  }

  for (int l = 0; l < NL_; ++l) {
    k_gemm64<0><<<dim3(3 * H_ / 64, S_ / 64), dim3(256), 0, stream>>>(
        hb_a, aiwb + (size_t)l * 3 * H_ * H_, attn_in_b + (size_t)l * 3 * H_, qkvb, S_, 3 * H_, H_);
    k_attn<<<dim3(S_ / 128, NH_, SPLITS_), dim3(256), 0, stream>>>(qkvb, Opart, Lpart);
    k_proj<<<dim3(H_ / 64, S_ / 32), dim3(256), 0, stream>>>(
        Opart, Lpart, aowb + (size_t)l * H_ * H_, attn_out_b + (size_t)l * H_, tmpb);
    k_add_ln<<<dim3(S_ / 4), dim3(256), 0, stream>>>(hb_a, tmpb, ln1_g + l * H_, ln1_b + l * H_);
    k_gemm128<1><<<dim3(FF_ / 128, S_ / 128), dim3(256), 0, stream>>>(
        hb_a, f1wb + (size_t)l * FF_ * H_, ff1_b + (size_t)l * FF_, ffhb, S_, FF_, H_);
    k_ff2<<<dim3(H_ / 64, S_ / 32), dim3(256), 0, stream>>>(
        ffhb, f2wb + (size_t)l * H_ * FF_, ff2_b + (size_t)l * H_, tmpb, FF_);
    k_add_ln<<<dim3(S_ / 4), dim3(256), 0, stream>>>(hb_a, tmpb, ln2_g + l * H_, ln2_b + l * H_);
  }

  k_ff2<<<dim3(H_ / 64, S_ / 32), dim3(256), 0, stream>>>(hb_a, fcwb, fc_b, tmpb, H_);
  int nxb = (V_ + 127) / 128;  // 79
  k_gsum<<<dim3(nxb, S_ / 128), dim3(256), 0, stream>>>(tmpb, owb, out_b, psums, S_, V_, H_);
  k_lse<<<dim3(S_ / 4), dim3(256), 0, stream>>>(psums, lse, nxb * 2);
  k_gout<<<dim3(nxb, S_ / 128), dim3(256), 0, stream>>>(tmpb, owb, out_b, lse, out, S_, V_, H_);
}